// Round 2
// baseline (1290.452 us; speedup 1.0000x reference)
//
#include <hip/hip_runtime.h>
#include <math.h>

#define B_    32
#define T_    128
#define D_    512
#define FF_   2048
#define E_    8
#define NL_   3
#define NF_   16
#define FEAT_ 200
#define BT_   4096   // B*T

// gate routing: 64 blocks x 64 tokens each -> 512 global atomics (vs 8192)
#define GB_   64
#define TPB_  (BT_ / GB_)   // 64 tokens per block

typedef short bf16x8 __attribute__((ext_vector_type(8)));
typedef float f32x4  __attribute__((ext_vector_type(4)));

__device__ inline unsigned short f2bf(float f) {
    unsigned u = __float_as_uint(f);
    unsigned r = (u + 0x7fffu + ((u >> 16) & 1u)) >> 16;   // RNE
    return (unsigned short)r;
}
// f = hi + lo + eps, |eps| <= 2^-18 |f|
__device__ inline void split_bf(float f, unsigned short& h, unsigned short& l) {
    h = f2bf(f);
    float fh = __uint_as_float(((unsigned)h) << 16);
    l = f2bf(f - fh);
}

// async HBM->LDS DMA, 16B/lane, no VGPR round-trip. LDS dest is
// wave-uniform base + lane*16 (HW rule).
__device__ __forceinline__ void ld_g2l(const unsigned short* g, unsigned short* l)
{
    __builtin_amdgcn_global_load_lds(
        (const __attribute__((address_space(1))) unsigned int*)(uintptr_t)g,
        (__attribute__((address_space(3))) unsigned int*)(uintptr_t)l,
        16, 0, 0);
}

// ---------------------------------------------------------------------------
// Split-bf16 MFMA GEMM, DMA-staged + ping-pong LDS double buffer (m97 style).
// C = A @ Bt^T + bias, fp32-equivalent precision (3-term MFMA).
// A as (Ah, Al) bf16 [M][K]; Bt as (Bh, Bl) [N][K] (K-contig).
// Tile 128x128, BK=32, 4 waves (2x2), each 64x64 via 4x4 of 16x16x32 MFMA.
// LDS: per buffer, 4 arrays (Ah,Al,Bh,Bl) of 128 rows x 32 shorts; within a
// row, global 16B-seg s lands at pos p = s ^ ((r>>1)&3) -> frag ds_read_b128
// is 2-way bank aliased (free).
// XCD-group swizzle: all gridDim.x n-tiles of one (m,z) group map to the same
// lin%8 -> same XCD L2 -> A tile re-reads are L2 hits, not HBM re-fetches.
// MODE 0: direct rows. MODE 2: A and C rows at offsets[z]+m (packed).
// ---------------------------------------------------------------------------
template <int MODE, bool SPLITOUT, bool RELU>
__global__ __launch_bounds__(256)
void mgemm_k(const unsigned short* __restrict__ Ah, const unsigned short* __restrict__ Al,
             const unsigned short* __restrict__ Bh, const unsigned short* __restrict__ Bl,
             const float* __restrict__ bias,
             float* __restrict__ Cf, unsigned short* __restrict__ Ch,
             unsigned short* __restrict__ Cl,
             int M, int K, int N, long strB, int strBias,
             const int* __restrict__ counts, const int* __restrict__ offsets,
             const int* __restrict__ tok_list)
{
    // ---- XCD-aware group remap (correctness-safe; bijective when gy*gz%8==0)
    int bn = blockIdx.x, bm = blockIdx.y, bz = blockIdx.z;
    {
        const int gx = gridDim.x, gy = gridDim.y, gz = gridDim.z;
        if (((gy * gz) & 7) == 0) {
            int lin = bn + gx * (bm + gy * bz);
            int xcd = lin & 7, r = lin >> 3;
            bn = r % gx;
            int g = xcd + 8 * (r / gx);
            bm = g % gy;
            bz = g / gy;
        }
    }
    const int z  = bz;
    const int m0 = bm * 128, n0 = bn * 128;
    int rows, rowoff = 0;
    if constexpr (MODE != 0) {
        rows = counts[z];
        if (m0 >= rows) return;
        rowoff = offsets[z];
    } else {
        rows = M;
    }
    const unsigned short* Bhb = Bh + (long)z * strB;
    const unsigned short* Blb = Bl + (long)z * strB;
    const float* biasb = bias + (long)z * strBias;

    // 2 buffers x 4 arrays x 4096 shorts (8 KB) = 64 KB
    __shared__ unsigned short S[2][4 * 4096];

    const int tid  = threadIdx.x;
    const int w    = tid >> 6, lane = tid & 63;
    const int wm = w & 1, wn = w >> 1;
    const int l15 = lane & 15, quad = lane >> 4;

    // staging map: wave w, issue j covers tile rows r = w*32 + (lane>>2) (+16*j)
    // LDS pos p = lane&3, global seg s = p ^ ((r>>1)&3) = p ^ ((lane>>3)&3)
    const int lrow0 = w * 32 + (lane >> 2);
    const int lrow1 = lrow0 + 16;
    const int sseg  = (lane & 3) ^ ((lane >> 3) & 3);
    const int lb0   = (w * 2 + 0) * 512;             // uniform short-offset in array
    const int lb1   = (w * 2 + 1) * 512;

    long ga0, ga1;
    if constexpr (MODE == 1) {
        int m_a = m0 + lrow0; if (m_a >= rows) m_a = rows - 1;
        int m_b = m0 + lrow1; if (m_b >= rows) m_b = rows - 1;
        ga0 = tok_list[z * BT_ + m_a];
        ga1 = tok_list[z * BT_ + m_b];
    } else if constexpr (MODE == 2) {
        int m_a = m0 + lrow0; if (m_a >= rows) m_a = rows - 1;
        int m_b = m0 + lrow1; if (m_b >= rows) m_b = rows - 1;
        ga0 = (long)rowoff + m_a;
        ga1 = (long)rowoff + m_b;
    } else {
        ga0 = m0 + lrow0;
        ga1 = m0 + lrow1;
    }
    const long aoff0 = ga0 * (long)K + sseg * 8;
    const long aoff1 = ga1 * (long)K + sseg * 8;
    const long boff0 = (long)(n0 + lrow0) * K + sseg * 8;
    const long boff1 = (long)(n0 + lrow1) * K + sseg * 8;

    f32x4 acc[4][4];
#pragma unroll
    for (int i = 0; i < 4; ++i)
#pragma unroll
        for (int j = 0; j < 4; ++j) acc[i][j] = (f32x4)0.f;

    const int xq = quad ^ ((l15 >> 1) & 3);          // swizzled read pos

    // ---- prologue: DMA tile 0 into buffer 0 ----
    {
        unsigned short* Sb = S[0];
        ld_g2l(Ah  + aoff0, Sb + 0 * 4096 + lb0);
        ld_g2l(Ah  + aoff1, Sb + 0 * 4096 + lb1);
        ld_g2l(Al  + aoff0, Sb + 1 * 4096 + lb0);
        ld_g2l(Al  + aoff1, Sb + 1 * 4096 + lb1);
        ld_g2l(Bhb + boff0, Sb + 2 * 4096 + lb0);
        ld_g2l(Bhb + boff1, Sb + 2 * 4096 + lb1);
        ld_g2l(Blb + boff0, Sb + 3 * 4096 + lb0);
        ld_g2l(Blb + boff1, Sb + 3 * 4096 + lb1);
    }

    unsigned short* Scur = S[0];
    unsigned short* Snxt = S[1];

    for (int k0 = 0; k0 < K; k0 += 32) {
        __syncthreads();        // drains DMA for tile k0 (in flight one full iter)

        if (k0 + 32 < K) {      // prefetch tile k0+32 into the other buffer
            int kn = k0 + 32;
            ld_g2l(Ah  + aoff0 + kn, Snxt + 0 * 4096 + lb0);
            ld_g2l(Ah  + aoff1 + kn, Snxt + 0 * 4096 + lb1);
            ld_g2l(Al  + aoff0 + kn, Snxt + 1 * 4096 + lb0);
            ld_g2l(Al  + aoff1 + kn, Snxt + 1 * 4096 + lb1);
            ld_g2l(Bhb + boff0 + kn, Snxt + 2 * 4096 + lb0);
            ld_g2l(Bhb + boff1 + kn, Snxt + 2 * 4096 + lb1);
            ld_g2l(Blb + boff0 + kn, Snxt + 3 * 4096 + lb0);
            ld_g2l(Blb + boff1 + kn, Snxt + 3 * 4096 + lb1);
        }

        bf16x8 ah4[4], al4[4], bh4[4], bl4[4];
#pragma unroll
        for (int i = 0; i < 4; ++i) {
            int ro = (wm * 64 + i * 16 + l15) * 32 + xq * 8;
            ah4[i] = *(const bf16x8*)&Scur[0 * 4096 + ro];
            al4[i] = *(const bf16x8*)&Scur[1 * 4096 + ro];
        }
#pragma unroll
        for (int j = 0; j < 4; ++j) {
            int ro = (wn * 64 + j * 16 + l15) * 32 + xq * 8;
            bh4[j] = *(const bf16x8*)&Scur[2 * 4096 + ro];
            bl4[j] = *(const bf16x8*)&Scur[3 * 4096 + ro];
        }
#pragma unroll
        for (int i = 0; i < 4; ++i)
#pragma unroll
            for (int j = 0; j < 4; ++j) {
                acc[i][j] = __builtin_amdgcn_mfma_f32_16x16x32_bf16(al4[i], bh4[j], acc[i][j], 0, 0, 0);
                acc[i][j] = __builtin_amdgcn_mfma_f32_16x16x32_bf16(ah4[i], bl4[j], acc[i][j], 0, 0, 0);
                acc[i][j] = __builtin_amdgcn_mfma_f32_16x16x32_bf16(ah4[i], bh4[j], acc[i][j], 0, 0, 0);
            }

        unsigned short* t = Scur; Scur = Snxt; Snxt = t;
    }

    // C/D layout: col = lane&15, row = quad*4 + reg
#pragma unroll
    for (int i = 0; i < 4; ++i) {
#pragma unroll
        for (int r = 0; r < 4; ++r) {
            int gm = m0 + wm * 64 + i * 16 + quad * 4 + r;
            if (MODE != 0 && gm >= rows) continue;
            long crow = (MODE != 0) ? ((long)rowoff + gm) : (long)gm;
#pragma unroll
            for (int j = 0; j < 4; ++j) {
                int col = n0 + wn * 64 + j * 16 + l15;
                float v = acc[i][j][r] + biasb[col];
                if constexpr (RELU) v = fmaxf(v, 0.f);
                if constexpr (SPLITOUT) {
                    unsigned short h, l;
                    split_bf(v, h, l);
                    Ch[crow * (long)N + col] = h;
                    Cl[crow * (long)N + col] = l;
                } else {
                    Cf[crow * (long)N + col] = v;
                }
            }
        }
    }
}

// ---------------------------------------------------------------------------
// fp32 SGEMM (embed GEMM K=200, batched pb@V). Optional fused split-bf16 out.
// ---------------------------------------------------------------------------
template <bool WF32, bool SPLIT>
__global__ __launch_bounds__(256)
void gemm_k(const float* __restrict__ A, const float* __restrict__ Bm,
            const float* __restrict__ bias, float* __restrict__ C,
            unsigned short* __restrict__ Oh, unsigned short* __restrict__ Ol,
            int K, int lda, int ldb, int ldc,
            long strA, long strB, long strC, int strBias)
{
    const int z  = blockIdx.z;
    const int m0 = blockIdx.y * 64, n0 = blockIdx.x * 64;
    const float* Ab    = A    + (long)z * strA;
    const float* Bb    = Bm   + (long)z * strB;
    const float* biasb = bias + (long)z * strBias;

    __shared__ float As[16][68];
    __shared__ float Bs[16][64];

    const int tid = threadIdx.x;
    const int tx  = tid & 15, ty = tid >> 4;
    const int ar  = tid >> 2;
    const int akc = (tid & 3) * 4;
    const float* Arow = Ab + (long)(m0 + ar) * lda;
    const int bkr = tid >> 4;
    const int bnc = (tid & 15) * 4;

    float acc[4][4];
#pragma unroll
    for (int i = 0; i < 4; ++i)
#pragma unroll
        for (int j = 0; j < 4; ++j) acc[i][j] = 0.f;

    for (int k0 = 0; k0 < K; k0 += 16) {
        if (k0 + 16 <= K) {
            float4 a = *(const float4*)(Arow + k0 + akc);
            As[akc + 0][ar] = a.x; As[akc + 1][ar] = a.y;
            As[akc + 2][ar] = a.z; As[akc + 3][ar] = a.w;
        } else {
#pragma unroll
            for (int j = 0; j < 4; ++j) {
                int kk = k0 + akc + j;
                As[akc + j][ar] = (kk < K) ? Arow[kk] : 0.f;
            }
        }
        {
            int kk = k0 + bkr;
            float4 b;
            if (kk < K) b = *(const float4*)(Bb + (long)kk * ldb + n0 + bnc);
            else        b = make_float4(0.f, 0.f, 0.f, 0.f);
            *(float4*)&Bs[bkr][bnc] = b;
        }
        __syncthreads();
#pragma unroll
        for (int k = 0; k < 16; ++k) {
            float4 av = *(const float4*)&As[k][ty * 4];
            float4 bv = *(const float4*)&Bs[k][tx * 4];
            float am[4] = {av.x, av.y, av.z, av.w};
            float bn[4] = {bv.x, bv.y, bv.z, bv.w};
#pragma unroll
            for (int i = 0; i < 4; ++i)
#pragma unroll
                for (int j = 0; j < 4; ++j)
                    acc[i][j] = fmaf(am[i], bn[j], acc[i][j]);
        }
        __syncthreads();
    }
#pragma unroll
    for (int i = 0; i < 4; ++i) {
        long base = ((long)z * strC) + (long)(m0 + ty * 4 + i) * ldc + n0 + tx * 4;
        const float* bp = biasb + n0 + tx * 4;
#pragma unroll
        for (int j = 0; j < 4; ++j) {
            float v = acc[i][j] + bp[j];
            if constexpr (WF32) C[base + j] = v;
            if constexpr (SPLIT) {
                unsigned short h, l;
                split_bf(v, h, l);
                Oh[base + j] = h;
                Ol[base + j] = l;
            }
        }
    }
}

// ---------------------------------------------------------------------------
// fp32 [R][C] -> split-bf16 [C][R] (hi, lo), batched over z
// ---------------------------------------------------------------------------
__global__ __launch_bounds__(256)
void transpose_split_k(const float* __restrict__ in,
                       unsigned short* __restrict__ oh, unsigned short* __restrict__ ol,
                       int R, int C, long strIn, long strOut)
{
    __shared__ float tile[32][33];
    const float* I = in + (long)blockIdx.z * strIn;
    unsigned short* OH = oh + (long)blockIdx.z * strOut;
    unsigned short* OL = ol + (long)blockIdx.z * strOut;
    int c0 = blockIdx.x * 32, r0 = blockIdx.y * 32;
    int tx = threadIdx.x & 31, ty = threadIdx.x >> 5;
#pragma unroll
    for (int i = 0; i < 4; ++i)
        tile[ty + i * 8][tx] = I[(long)(r0 + ty + i * 8) * C + c0 + tx];
    __syncthreads();
#pragma unroll
    for (int i = 0; i < 4; ++i) {
        unsigned short h, l;
        split_bf(tile[tx][ty + i * 8], h, l);
        long o = (long)(c0 + ty + i * 8) * R + r0 + tx;
        OH[o] = h; OL[o] = l;
    }
}

__global__ void bias_cat_k(const float* __restrict__ a, const float* __restrict__ b,
                           float* __restrict__ o)
{
    int i = blockIdx.x * 256 + threadIdx.x;   // 1024
    o[i] = (i < D_) ? a[i] : b[i - D_];
}

// ---------------------------------------------------------------------------
__global__ void embed_gather_k(const int* __restrict__ src,
                               const float* __restrict__ table,
                               float* __restrict__ emb)
{
    int t = blockIdx.x;
    int v = src[t];
    for (int k = threadIdx.x; k < FEAT_; k += 256)
        emb[t * FEAT_ + k] = table[v * FEAT_ + k];
}

__global__ __launch_bounds__(256)
void pb_k(const float* __restrict__ frac, const float* __restrict__ pbW,
          const float* __restrict__ pbb, const float* __restrict__ pba,
          float* __restrict__ pb)
{
    int idx = blockIdx.x * 256 + threadIdx.x;
    int b = idx >> 14;
    int i = (idx >> 7) & 127;
    int j = idx & 127;
    float diff = (frac[b * T_ + j] - frac[b * T_ + i]) * 10.0f;
    float s = 0.f;
#pragma unroll
    for (int f = 0; f < NF_; ++f)
        s = fmaf(cosf(fmaf(diff, pbW[f], pbb[f])), pba[f], s);
    pb[idx] = s;
}

// kv[b,c] = sum_t K[b,t,c]*V[b,t,c]; K,V interleaved in KVb [BT][1024]
__global__ __launch_bounds__(256)
void kv_k(const float* __restrict__ KV, float* __restrict__ kv)
{
    int idx = blockIdx.x * 256 + threadIdx.x;
    int b = idx >> 9, c = idx & 511;
    const float* Kp = KV + (long)b * T_ * 1024 + c;
    float s = 0.f;
    for (int t = 0; t < T_; ++t) {
        const float* p = Kp + t * 1024;
        s = fmaf(p[0], p[D_], s);
    }
    kv[idx] = s;
}

// LayerNorm(x + add) -> out fp32 + split bf16
__global__ __launch_bounds__(256)
void ln_res_k(const float* __restrict__ x, const float* __restrict__ add,
              const float* __restrict__ g, const float* __restrict__ b,
              float* __restrict__ out, unsigned short* __restrict__ oh,
              unsigned short* __restrict__ ol)
{
    int wave = threadIdx.x >> 6, lane = threadIdx.x & 63;
    int row = blockIdx.x * 4 + wave;
    const float* xr = x   + (long)row * D_ + lane * 8;
    const float* ar = add + (long)row * D_ + lane * 8;
    float v[8]; float s = 0.f;
#pragma unroll
    for (int j = 0; j < 8; ++j) { v[j] = xr[j] + ar[j]; s += v[j]; }
#pragma unroll
    for (int off = 32; off > 0; off >>= 1) s += __shfl_xor(s, off, 64);
    float mean = s * (1.f / D_);
    float q = 0.f;
#pragma unroll
    for (int j = 0; j < 8; ++j) { float d = v[j] - mean; q += d * d; }
#pragma unroll
    for (int off = 32; off > 0; off >>= 1) q += __shfl_xor(q, off, 64);
    float inv = rsqrtf(q * (1.f / D_) + 1e-5f);
    float* orow = out + (long)row * D_ + lane * 8;
    unsigned short* hrow = oh + (long)row * D_ + lane * 8;
    unsigned short* lrow = ol + (long)row * D_ + lane * 8;
#pragma unroll
    for (int j = 0; j < 8; ++j) {
        int c = lane * 8 + j;
        float o = (v[j] - mean) * inv * g[c] + b[c];
        orow[j] = o;
        unsigned short hh, ll;
        split_bf(o, hh, ll);
        hrow[j] = hh; lrow[j] = ll;
    }
}

// LayerNorm(x + w0*eo0 + w1*eo1) -> out fp32 + split bf16
__global__ __launch_bounds__(256)
void ln_moe_k(const float* __restrict__ x, const float* __restrict__ eo,
              const int* __restrict__ tok_slot, const float* __restrict__ tok_w,
              const int* __restrict__ offsets,
              const float* __restrict__ g, const float* __restrict__ b,
              float* __restrict__ out, unsigned short* __restrict__ oh,
              unsigned short* __restrict__ ol)
{
    int wave = threadIdx.x >> 6, lane = threadIdx.x & 63;
    int row = blockIdx.x * 4 + wave;
    int  c0 = tok_slot[row * 2], c1 = tok_slot[row * 2 + 1];
    float w0 = tok_w[row * 2],  w1 = tok_w[row * 2 + 1];
    long r0 = offsets[c0 >> 12] + (c0 & 4095);
    long r1 = offsets[c1 >> 12] + (c1 & 4095);
    const float* xr = x  + (long)row * D_ + lane * 8;
    const float* e0 = eo + r0 * D_ + lane * 8;
    const float* e1 = eo + r1 * D_ + lane * 8;
    float v[8]; float s = 0.f;
#pragma unroll
    for (int j = 0; j < 8; ++j) {
        v[j] = xr[j] + w0 * e0[j] + w1 * e1[j];
        s += v[j];
    }
#pragma unroll
    for (int off = 32; off > 0; off >>= 1) s += __shfl_xor(s, off, 64);
    float mean = s * (1.f / D_);
    float q = 0.f;
#pragma unroll
    for (int j = 0; j < 8; ++j) { float d = v[j] - mean; q += d * d; }
#pragma unroll
    for (int off = 32; off > 0; off >>= 1) q += __shfl_xor(q, off, 64);
    float inv = rsqrtf(q * (1.f / D_) + 1e-5f);
    float* orow = out + (long)row * D_ + lane * 8;
    unsigned short* hrow = oh + (long)row * D_ + lane * 8;
    unsigned short* lrow = ol + (long)row * D_ + lane * 8;
#pragma unroll
    for (int j = 0; j < 8; ++j) {
        int c = lane * 8 + j;
        float o = (v[j] - mean) * inv * g[c] + b[c];
        orow[j] = o;
        unsigned short hh, ll;
        split_bf(o, hh, ll);
        hrow[j] = hh; lrow[j] = ll;
    }
}

// ---------------------------------------------------------------------------
// Gating + routing, block-aggregated.
// 64 blocks x 64 tokens. Per token: one wave computes the 8 logits
// (lane = expert(l&7) x d-chunk(l>>3), 3x shfl_xor chunk-reduce), gathers
// logits to all lanes, per-lane softmax + top2; lane 0 takes LDS-local slots.
// One global atomicAdd per (block, expert) -> 512 total.
// ---------------------------------------------------------------------------
__global__ __launch_bounds__(256)
void gate_k(const float* __restrict__ x, const float* __restrict__ gW,
            const float* __restrict__ gb, int* __restrict__ counts,
            int* __restrict__ tok_list, int* __restrict__ tok_slot,
            float* __restrict__ tok_w)
{
    __shared__ int scnt[E_];
    __shared__ int sbase[E_];
    __shared__ int sent[TPB_][2];      // (e<<12) | local_slot per token entry

    const int wave = threadIdx.x >> 6, lane = threadIdx.x & 63;
    const int e  = lane & 7;
    const int ch = lane >> 3;
    const int t0 = blockIdx.x * TPB_;

    if (threadIdx.x < E_) scnt[threadIdx.x] = 0;
    __syncthreads();

    for (int it = 0; it < TPB_ / 4; ++it) {
        const int tl = it * 4 + wave;
        const int t  = t0 + tl;

        // logit(e) partial over d-chunk ch (64 d's)
        const float4* x4 = (const float4*)(x + (long)t * D_ + ch * 64);
        const float*  wr = gW + (long)ch * 64 * E_ + e;
        float acc = 0.f;
#pragma unroll
        for (int d4 = 0; d4 < 16; ++d4) {
            float4 xv = x4[d4];
            acc = fmaf(xv.x, wr[(d4 * 4 + 0) * 8], acc);
            acc = fmaf(xv.y, wr[(d4 * 4 + 1) * 8], acc);
            acc = fmaf(xv.z, wr[(d4 * 4 + 2) * 8], acc);
            acc = fmaf(xv.w, wr[(d4 * 4 + 3) * 8], acc);
        }
        // reduce across the 8 chunk-groups (lanes differing in bits 3..5)
        acc += __shfl_xor(acc, 8, 64);
        acc += __shfl_xor(acc, 16, 64);
        acc += __shfl_xor(acc, 32, 64);
        acc += gb[e];                    // every lane now holds logit(lane&7)

        // gather all 8 logits into every lane (uniform, non-divergent)
        float lg[8];
#pragma unroll
        for (int ee = 0; ee < 8; ++ee)
            lg[ee] = __shfl(acc, (lane & 56) | ee, 64);

        // per-lane softmax + top2 (replicates old lane-0 serial code)
        float m = lg[0];
#pragma unroll
        for (int ee = 1; ee < 8; ++ee) m = fmaxf(m, lg[ee]);
        float p[8]; float s = 0.f;
#pragma unroll
        for (int ee = 0; ee < 8; ++ee) { p[ee] = expf(lg[ee] - m); s += p[ee]; }
        float inv = 1.f / s;
        int e1 = 0;
#pragma unroll
        for (int ee = 1; ee < 8; ++ee) if (p[ee] > p[e1]) e1 = ee;
        int e2 = (e1 == 0) ? 1 : 0;
#pragma unroll
        for (int ee = 0; ee < 8; ++ee) {
            if (ee == e1) continue;
            if (p[ee] > p[e2]) e2 = ee;
        }

        if (lane == 0) {
            int ls1 = atomicAdd(&scnt[e1], 1);
            int ls2 = atomicAdd(&scnt[e2], 1);
            sent[tl][0] = (e1 << 12) | ls1;
            sent[tl][1] = (e2 << 12) | ls2;
            tok_w[t * 2]     = p[e1] * inv;
            tok_w[t * 2 + 1] = p[e2] * inv;
        }
    }
    __syncthreads();

    if (threadIdx.x < E_)
        sbase[threadIdx.x] = atomicAdd(&counts[threadIdx.x], scnt[threadIdx.x]);
    __syncthreads();

    for (int tl = threadIdx.x; tl < TPB_; tl += 256) {
        const int t = t0 + tl;
#pragma unroll
        for (int kk = 0; kk < 2; ++kk) {
            int v    = sent[tl][kk];
            int ee   = v >> 12;
            int slot = sbase[ee] + (v & 4095);
            tok_list[ee * BT_ + slot] = t;
            tok_slot[t * 2 + kk] = (ee << 12) | slot;
        }
    }
}

// pack x rows (split pair) into expert-slot order: xg[offsets[e]+slot] = x[t]
__global__ __launch_bounds__(256)
void gather_tok_k(const unsigned short* __restrict__ xh,
                  const unsigned short* __restrict__ xl,
                  const int* __restrict__ tok_slot, const int* __restrict__ offsets,
                  unsigned short* __restrict__ xgh, unsigned short* __restrict__ xgl)
{
    int wid  = blockIdx.x * 4 + (threadIdx.x >> 6);   // [0, 2*BT)
    int lane = threadIdx.x & 63;
    int t = wid >> 1, k = wid & 1;
    int c = tok_slot[t * 2 + k];
    long r = offsets[c >> 12] + (c & 4095);
    const bf16x8* sh = (const bf16x8*)(xh + (long)t * D_);
    const bf16x8* sl = (const bf16x8*)(xl + (long)t * D_);
    ((bf16x8*)(xgh + r * D_))[lane] = sh[lane];
    ((bf16x8*)(xgl + r * D_))[lane] = sl[lane];
}

__global__ void zero_counts_k(int* __restrict__ counts)
{
    if (threadIdx.x < E_) counts[threadIdx.x] = 0;
}

__global__ void scan_k(const int* __restrict__ counts, int* __restrict__ offsets)
{
    if (threadIdx.x == 0) {
        int s = 0;
        for (int e = 0; e < E_; ++e) { offsets[e] = s; s += counts[e]; }
    }
}

// ---------------------------------------------------------------------------
extern "C" void kernel_launch(void* const* d_in, const int* in_sizes, int n_in,
                              void* d_out, int out_size, void* d_ws, size_t ws_size,
                              hipStream_t stream)
{
    const int*   src   = (const int*)  d_in[0];
    const float* frac  = (const float*)d_in[1];
    const float* table = (const float*)d_in[2];
    const float* W_m2v = (const float*)d_in[3];
    const float* b_m2v = (const float*)d_in[4];
    const float* pbW   = (const float*)d_in[5];
    const float* pbb   = (const float*)d_in[6];
    const float* pba   = (const float*)d_in[7];
    const float* Wk    = (const float*)d_in[8];
    const float* bk    = (const float*)d_in[9];
    const float* Wv    = (const float*)d_in[10];
    const float* bv    = (const float*)d_in[11];
    const float* Wo    = (const float*)d_in[12];
    const float* bo    = (const float*)d_in[13];
    const float* ln1g  = (const float*)d_in[14];
    const float* ln1b  = (const float*)d_in[15];
    const float* ln2g  = (const float*)d_in[16];
    const float* ln2b  = (const float*)d_in[17];
    const float* gW    = (const float*)d_in[18];
    const float* gb    = (const float*)d_in[19];
    const float* eW1   = (const float*)d_in[20];
    const float* eb1   = (const float*)d_in[21];
    const float* eW2   = (const float*)d_in[22];
    const float* eb2   = (const float*)d_in[23];

    // ---- workspace layout (persistent) ----
    float* ws   = (float*)d_ws;
    float* x    = ws;  ws += (long)BT_ * D_;
    float* pb   = ws;  ws += (long)B_ * T_ * T_;
    float* eo   = ws;  ws += (long)2 * BT_ * D_;
    float* kv   = ws;  ws += B_ * D_;
    float* tokw = ws;  ws += 2 * BT_;
    float* kvbias = ws; ws += 2 * D_;
    unsigned short* us = (unsigned short*)ws;
    unsigned short* x_h   = us;  us += (long)BT_ * D_;
    unsigned short* x_l   = us;  us += (long)BT_ * D_;
    unsigned short* Wkv_h = us;  us += (long)2 * D_ * D_;   // [Wk^T ; Wv^T]
    unsigned short* Wkv_l = us;  us += (long)2 * D_ * D_;
    unsigned short* Wo_h  = us;  us += (long)D_ * D_;
    unsigned short* Wo_l  = us;  us += (long)D_ * D_;
    unsigned short* e1_h  = us;  us += (long)E_ * FF_ * D_;
    unsigned short* e1_l  = us;  us += (long)E_ * FF_ * D_;
    unsigned short* e2_h  = us;  us += (long)E_ * D_ * FF_;
    unsigned short* e2_l  = us;  us += (long)E_ * D_ * FF_;
    int* counts  = (int*)us;
    int* offsets = counts + 8;
    int* toklist = offsets + 8;
    int* tokslot = toklist + E_ * BT_;
    // xg (packed expert-order x, split pair) aliases eo:
    //   xg written after gate, read in e1; eo written in e2, read in ln_moe.
    unsigned short* xg_h = (unsigned short*)eo;              // [2*BT][D]
    unsigned short* xg_l = xg_h + (long)2 * BT_ * D_;
    // ---- aliased region: {emb, KVb, tmp, wv pair} vs {h pair} ----
    char* ar = (char*)(tokslot + 2 * BT_);
    ar = (char*)(((size_t)ar + 255) & ~(size_t)255);
    unsigned short* h_h = (unsigned short*)ar;               // [2*BT][FF]
    unsigned short* h_l = h_h + (long)2 * BT_ * FF_;
    float* emb  = (float*)ar;
    float* KVb  = emb + (long)BT_ * FEAT_;                   // [BT][1024]
    float* tmp  = KVb + (long)BT_ * 2 * D_;
    unsigned short* wv_h = (unsigned short*)(tmp + (long)BT_ * D_);
    unsigned short* wv_l = wv_h + (long)BT_ * D_;

    // ---- embedder (fp32, fused split epilogue) ----
    embed_gather_k<<<BT_, 256, 0, stream>>>(src, table, emb);
    gemm_k<true, true><<<dim3(8, 64, 1), 256, 0, stream>>>(
        emb, W_m2v, b_m2v, x, x_h, x_l, FEAT_, FEAT_, D_, D_, 0, 0, 0, 0);

    // ---- fourier positional bias ----
    pb_k<<<(B_ * T_ * T_) / 256, 256, 0, stream>>>(frac, pbW, pbb, pba, pb);

    for (int i = 0; i < NL_; ++i) {
        // weight transposes: fp32 [K][N] -> split bf16 [N][K]
        transpose_split_k<<<dim3(16, 16, 1), 256, 0, stream>>>(
            Wk + (long)i * D_ * D_, Wkv_h, Wkv_l, D_, D_, 0, 0);
        transpose_split_k<<<dim3(16, 16, 1), 256, 0, stream>>>(
            Wv + (long)i * D_ * D_, Wkv_h + (long)D_ * D_, Wkv_l + (long)D_ * D_,
            D_, D_, 0, 0);
        transpose_split_k<<<dim3(16, 16, 1), 256, 0, stream>>>(
            Wo + (long)i * D_ * D_, Wo_h, Wo_l, D_, D_, 0, 0);
        transpose_split_k<<<dim3(64, 16, E_), 256, 0, stream>>>(
            eW1 + (long)i * E_ * D_ * FF_, e1_h, e1_l, D_, FF_,
            (long)D_ * FF_, (long)FF_ * D_);
        transpose_split_k<<<dim3(16, 64, E_), 256, 0, stream>>>(
            eW2 + (long)i * E_ * FF_ * D_, e2_h, e2_l, FF_, D_,
            (long)FF_ * D_, (long)D_ * FF_);
        bias_cat_k<<<4, 256, 0, stream>>>(bk + i * D_, bv + i * D_, kvbias);

        // merged K|V projection: [BT][1024] = x @ [Wk Wv]
        mgemm_k<0, false, false><<<dim3(8, 32, 1), 256, 0, stream>>>(
            x_h, x_l, Wkv_h, Wkv_l, kvbias,
            KVb, nullptr, nullptr, BT_, D_, 2 * D_, 0, 0,
            nullptr, nullptr, nullptr);

        kv_k<<<(B_ * D_) / 256, 256, 0, stream>>>(KVb, kv);

        // wv[b] = pb[b] @ V[b] + kv[b]  (fp32, fused split epilogue -> wv pair)
        gemm_k<false, true><<<dim3(8, 2, B_), 256, 0, stream>>>(
            pb, KVb + D_, kv, nullptr, wv_h, wv_l, T_, T_, 2 * D_, D_,
            (long)T_ * T_, (long)T_ * 2 * D_, (long)T_ * D_, D_);

        // attention output projection
        mgemm_k<0, false, false><<<dim3(4, 32, 1), 256, 0, stream>>>(
            wv_h, wv_l, Wo_h, Wo_l, bo + i * D_,
            tmp, nullptr, nullptr, BT_, D_, D_, 0, 0, nullptr, nullptr, nullptr);

        // x = LN1(x + tmp)
        ln_res_k<<<BT_ / 4, 256, 0, stream>>>(x, tmp, ln1g + i * D_, ln1b + i * D_,
                                              x, x_h, x_l);

        // gating + routing (block-aggregated atomics)
        zero_counts_k<<<1, 64, 0, stream>>>(counts);
        gate_k<<<GB_, 256, 0, stream>>>(x, gW + (long)i * D_ * E_, gb + i * E_,
                                        counts, toklist, tokslot, tokw);
        scan_k<<<1, 1, 0, stream>>>(counts, offsets);

        // pack tokens into expert order (contiguous A for expert GEMMs)
        gather_tok_k<<<(2 * BT_) / 4, 256, 0, stream>>>(
            x_h, x_l, tokslot, offsets, xg_h, xg_l);

        // MoE expert GEMMs (split MFMA, packed contiguous A)
        mgemm_k<2, true, true><<<dim3(16, 32, E_), 256, 0, stream>>>(
            xg_h, xg_l, e1_h, e1_l, eb1 + (long)i * E_ * FF_,
            nullptr, h_h, h_l, 0, D_, FF_,
            (long)FF_ * D_, FF_, counts, offsets, toklist);
        mgemm_k<2, false, false><<<dim3(4, 32, E_), 256, 0, stream>>>(
            h_h, h_l, e2_h, e2_l, eb2 + (long)i * E_ * D_,
            eo, nullptr, nullptr, 0, FF_, D_,
            (long)D_ * FF_, D_, counts, offsets, toklist);

        // x = LN2(x + w0*eo0 + w1*eo1)
        float* dst = (i == NL_ - 1) ? (float*)d_out : x;
        ln_moe_k<<<BT_ / 4, 256, 0, stream>>>(x, eo, tokslot, tokw, offsets,
                                              ln2g + i * D_, ln2b + i * D_,
                                              dst, x_h, x_l);
    }
}

// Round 3
// 1225.627 us; speedup vs baseline: 1.0529x; 1.0529x over previous
//
#include <hip/hip_runtime.h>
#include <math.h>

#define B_    32
#define T_    128
#define D_    512
#define FF_   2048
#define E_    8
#define NL_   3
#define NF_   16
#define FEAT_ 200
#define BT_   4096   // B*T

// gate routing: 64 blocks x 64 tokens each -> 512 global atomics (vs 8192)
#define GB_   64
#define TPB_  (BT_ / GB_)   // 64 tokens per block

typedef short bf16x8 __attribute__((ext_vector_type(8)));
typedef float f32x4  __attribute__((ext_vector_type(4)));

__device__ inline unsigned short f2bf(float f) {
    unsigned u = __float_as_uint(f);
    unsigned r = (u + 0x7fffu + ((u >> 16) & 1u)) >> 16;   // RNE
    return (unsigned short)r;
}
// f = hi + lo + eps, |eps| <= 2^-18 |f|
__device__ inline void split_bf(float f, unsigned short& h, unsigned short& l) {
    h = f2bf(f);
    float fh = __uint_as_float(((unsigned)h) << 16);
    l = f2bf(f - fh);
}

// async HBM->LDS DMA, 16B/lane, no VGPR round-trip. LDS dest is
// wave-uniform base + lane*16 (HW rule).
__device__ __forceinline__ void ld_g2l(const unsigned short* g, unsigned short* l)
{
    __builtin_amdgcn_global_load_lds(
        (const __attribute__((address_space(1))) unsigned int*)(uintptr_t)g,
        (__attribute__((address_space(3))) unsigned int*)(uintptr_t)l,
        16, 0, 0);
}

// ---------------------------------------------------------------------------
// Split-bf16 MFMA GEMM, DMA-staged + ping-pong LDS double buffer.
// C = A @ Bt^T + bias, fp32-equivalent precision (3-term MFMA).
// A as (Ah, Al) bf16 [M][K]; Bt as (Bh, Bl) [N][K] (K-contig).
// Tile 64x128 (M x N), BK=32, 4 waves (2x2), each wave 32x64 via 2x4 of
// 16x16x32 MFMA. 64x128 tile => 24 KB/buffer, 48 KB total => 3 blocks/CU
// (vs 2 at 128x128): +50% resident waves to hide the per-iter DMA drain.
// LDS per buffer (shorts): Ah[64*32]@0, Al@2048, Bh[128*32]@4096, Bl@8192.
// Within a row, global 16B-seg s lands at pos p = s ^ ((r>>1)&3) -> frag
// ds_read_b128 is 2-way bank aliased (free).
// MODE 0: direct rows. MODE 1: A rows via tok_list[z], C rows offsets[z]+m.
// MODE 2: A and C rows at offsets[z]+m.
// ---------------------------------------------------------------------------
template <int MODE, bool SPLITOUT, bool RELU>
__global__ __launch_bounds__(256)
void mgemm_k(const unsigned short* __restrict__ Ah, const unsigned short* __restrict__ Al,
             const unsigned short* __restrict__ Bh, const unsigned short* __restrict__ Bl,
             const float* __restrict__ bias,
             float* __restrict__ Cf, unsigned short* __restrict__ Ch,
             unsigned short* __restrict__ Cl,
             int M, int K, int N, long strB, int strBias,
             const int* __restrict__ counts, const int* __restrict__ offsets,
             const int* __restrict__ tok_list)
{
    const int z  = blockIdx.z;
    const int m0 = blockIdx.y * 64, n0 = blockIdx.x * 128;
    int rows, rowoff = 0;
    if constexpr (MODE != 0) {
        rows = counts[z];
        if (m0 >= rows) return;
        rowoff = offsets[z];
    } else {
        rows = M;
    }
    const unsigned short* Bhb = Bh + (long)z * strB;
    const unsigned short* Blb = Bl + (long)z * strB;
    const float* biasb = bias + (long)z * strBias;

    // 2 buffers x 12288 shorts (24 KB) = 48 KB
    __shared__ unsigned short S[2][12288];

    const int tid  = threadIdx.x;
    const int w    = tid >> 6, lane = tid & 63;
    const int wm = w & 1, wn = w >> 1;
    const int l15 = lane & 15, quad = lane >> 4;

    // staging map: A row = w*16 + (lane>>2) (1 load/wave/array);
    // B rows = w*32 + (lane>>2) (+16) (2 loads/wave/array).
    // LDS pos p = lane&3, global seg s = p ^ ((r>>1)&3) = p ^ ((lane>>3)&3)
    // (row bases are multiples of 16 so the formula is base-independent).
    const int arow  = w * 16 + (lane >> 2);
    const int brow0 = w * 32 + (lane >> 2);
    const int brow1 = brow0 + 16;
    const int sseg  = (lane & 3) ^ ((lane >> 3) & 3);
    const int laA   = w * 512;                  // uniform short-offset in A array
    const int lbB0  = w * 1024;                 // uniform short-offset in B array
    const int lbB1  = w * 1024 + 512;

    long gaA;
    if constexpr (MODE == 1) {
        int m_a = m0 + arow; if (m_a >= rows) m_a = rows - 1;
        gaA = tok_list[z * BT_ + m_a];
    } else if constexpr (MODE == 2) {
        int m_a = m0 + arow; if (m_a >= rows) m_a = rows - 1;
        gaA = (long)rowoff + m_a;
    } else {
        gaA = m0 + arow;
    }
    const long aoff  = gaA * (long)K + sseg * 8;
    const long boff0 = (long)(n0 + brow0) * K + sseg * 8;
    const long boff1 = (long)(n0 + brow1) * K + sseg * 8;

    f32x4 acc[2][4];
#pragma unroll
    for (int i = 0; i < 2; ++i)
#pragma unroll
        for (int j = 0; j < 4; ++j) acc[i][j] = (f32x4)0.f;

    const int xq = quad ^ ((l15 >> 1) & 3);          // swizzled read pos

    // ---- prologue: DMA tile 0 into buffer 0 ----
    {
        unsigned short* Sb = S[0];
        ld_g2l(Ah  + aoff,  Sb + 0    + laA);
        ld_g2l(Al  + aoff,  Sb + 2048 + laA);
        ld_g2l(Bhb + boff0, Sb + 4096 + lbB0);
        ld_g2l(Bhb + boff1, Sb + 4096 + lbB1);
        ld_g2l(Blb + boff0, Sb + 8192 + lbB0);
        ld_g2l(Blb + boff1, Sb + 8192 + lbB1);
    }

    unsigned short* Scur = S[0];
    unsigned short* Snxt = S[1];

    for (int k0 = 0; k0 < K; k0 += 32) {
        __syncthreads();        // drains DMA for tile k0 (in flight one full iter)

        if (k0 + 32 < K) {      // prefetch tile k0+32 into the other buffer
            int kn = k0 + 32;
            ld_g2l(Ah  + aoff  + kn, Snxt + 0    + laA);
            ld_g2l(Al  + aoff  + kn, Snxt + 2048 + laA);
            ld_g2l(Bhb + boff0 + kn, Snxt + 4096 + lbB0);
            ld_g2l(Bhb + boff1 + kn, Snxt + 4096 + lbB1);
            ld_g2l(Blb + boff0 + kn, Snxt + 8192 + lbB0);
            ld_g2l(Blb + boff1 + kn, Snxt + 8192 + lbB1);
        }

        bf16x8 ah2[2], al2[2], bh4[4], bl4[4];
#pragma unroll
        for (int i = 0; i < 2; ++i) {
            int ro = (wm * 32 + i * 16 + l15) * 32 + xq * 8;
            ah2[i] = *(const bf16x8*)&Scur[0    + ro];
            al2[i] = *(const bf16x8*)&Scur[2048 + ro];
        }
#pragma unroll
        for (int j = 0; j < 4; ++j) {
            int ro = (wn * 64 + j * 16 + l15) * 32 + xq * 8;
            bh4[j] = *(const bf16x8*)&Scur[4096 + ro];
            bl4[j] = *(const bf16x8*)&Scur[8192 + ro];
        }
#pragma unroll
        for (int i = 0; i < 2; ++i)
#pragma unroll
            for (int j = 0; j < 4; ++j) {
                acc[i][j] = __builtin_amdgcn_mfma_f32_16x16x32_bf16(al2[i], bh4[j], acc[i][j], 0, 0, 0);
                acc[i][j] = __builtin_amdgcn_mfma_f32_16x16x32_bf16(ah2[i], bl4[j], acc[i][j], 0, 0, 0);
                acc[i][j] = __builtin_amdgcn_mfma_f32_16x16x32_bf16(ah2[i], bh4[j], acc[i][j], 0, 0, 0);
            }

        unsigned short* t = Scur; Scur = Snxt; Snxt = t;
    }

    // C/D layout: col = lane&15, row = quad*4 + reg
#pragma unroll
    for (int i = 0; i < 2; ++i) {
#pragma unroll
        for (int r = 0; r < 4; ++r) {
            int gm = m0 + wm * 32 + i * 16 + quad * 4 + r;
            if (MODE != 0 && gm >= rows) continue;
            long crow = (MODE != 0) ? ((long)rowoff + gm) : (long)gm;
#pragma unroll
            for (int j = 0; j < 4; ++j) {
                int col = n0 + wn * 64 + j * 16 + l15;
                float v = acc[i][j][r] + biasb[col];
                if constexpr (RELU) v = fmaxf(v, 0.f);
                if constexpr (SPLITOUT) {
                    unsigned short h, l;
                    split_bf(v, h, l);
                    Ch[crow * (long)N + col] = h;
                    Cl[crow * (long)N + col] = l;
                } else {
                    Cf[crow * (long)N + col] = v;
                }
            }
        }
    }
}

// ---------------------------------------------------------------------------
// fp32 SGEMM (embed GEMM K=200, batched pb@V). Optional fused split-bf16 out.
// ---------------------------------------------------------------------------
template <bool WF32, bool SPLIT>
__global__ __launch_bounds__(256)
void gemm_k(const float* __restrict__ A, const float* __restrict__ Bm,
            const float* __restrict__ bias, float* __restrict__ C,
            unsigned short* __restrict__ Oh, unsigned short* __restrict__ Ol,
            int K, int lda, int ldb, int ldc,
            long strA, long strB, long strC, int strBias)
{
    const int z  = blockIdx.z;
    const int m0 = blockIdx.y * 64, n0 = blockIdx.x * 64;
    const float* Ab    = A    + (long)z * strA;
    const float* Bb    = Bm   + (long)z * strB;
    const float* biasb = bias + (long)z * strBias;

    __shared__ float As[16][68];
    __shared__ float Bs[16][64];

    const int tid = threadIdx.x;
    const int tx  = tid & 15, ty = tid >> 4;
    const int ar  = tid >> 2;
    const int akc = (tid & 3) * 4;
    const float* Arow = Ab + (long)(m0 + ar) * lda;
    const int bkr = tid >> 4;
    const int bnc = (tid & 15) * 4;

    float acc[4][4];
#pragma unroll
    for (int i = 0; i < 4; ++i)
#pragma unroll
        for (int j = 0; j < 4; ++j) acc[i][j] = 0.f;

    for (int k0 = 0; k0 < K; k0 += 16) {
        if (k0 + 16 <= K) {
            float4 a = *(const float4*)(Arow + k0 + akc);
            As[akc + 0][ar] = a.x; As[akc + 1][ar] = a.y;
            As[akc + 2][ar] = a.z; As[akc + 3][ar] = a.w;
        } else {
#pragma unroll
            for (int j = 0; j < 4; ++j) {
                int kk = k0 + akc + j;
                As[akc + j][ar] = (kk < K) ? Arow[kk] : 0.f;
            }
        }
        {
            int kk = k0 + bkr;
            float4 b;
            if (kk < K) b = *(const float4*)(Bb + (long)kk * ldb + n0 + bnc);
            else        b = make_float4(0.f, 0.f, 0.f, 0.f);
            *(float4*)&Bs[bkr][bnc] = b;
        }
        __syncthreads();
#pragma unroll
        for (int k = 0; k < 16; ++k) {
            float4 av = *(const float4*)&As[k][ty * 4];
            float4 bv = *(const float4*)&Bs[k][tx * 4];
            float am[4] = {av.x, av.y, av.z, av.w};
            float bn[4] = {bv.x, bv.y, bv.z, bv.w};
#pragma unroll
            for (int i = 0; i < 4; ++i)
#pragma unroll
                for (int j = 0; j < 4; ++j)
                    acc[i][j] = fmaf(am[i], bn[j], acc[i][j]);
        }
        __syncthreads();
    }
#pragma unroll
    for (int i = 0; i < 4; ++i) {
        long base = ((long)z * strC) + (long)(m0 + ty * 4 + i) * ldc + n0 + tx * 4;
        const float* bp = biasb + n0 + tx * 4;
#pragma unroll
        for (int j = 0; j < 4; ++j) {
            float v = acc[i][j] + bp[j];
            if constexpr (WF32) C[base + j] = v;
            if constexpr (SPLIT) {
                unsigned short h, l;
                split_bf(v, h, l);
                Oh[base + j] = h;
                Ol[base + j] = l;
            }
        }
    }
}

// ---------------------------------------------------------------------------
// fp32 [R][C] -> split-bf16 [C][R] (hi, lo), batched over z
// ---------------------------------------------------------------------------
__global__ __launch_bounds__(256)
void transpose_split_k(const float* __restrict__ in,
                       unsigned short* __restrict__ oh, unsigned short* __restrict__ ol,
                       int R, int C, long strIn, long strOut)
{
    __shared__ float tile[32][33];
    const float* I = in + (long)blockIdx.z * strIn;
    unsigned short* OH = oh + (long)blockIdx.z * strOut;
    unsigned short* OL = ol + (long)blockIdx.z * strOut;
    int c0 = blockIdx.x * 32, r0 = blockIdx.y * 32;
    int tx = threadIdx.x & 31, ty = threadIdx.x >> 5;
#pragma unroll
    for (int i = 0; i < 4; ++i)
        tile[ty + i * 8][tx] = I[(long)(r0 + ty + i * 8) * C + c0 + tx];
    __syncthreads();
#pragma unroll
    for (int i = 0; i < 4; ++i) {
        unsigned short h, l;
        split_bf(tile[tx][ty + i * 8], h, l);
        long o = (long)(c0 + ty + i * 8) * R + r0 + tx;
        OH[o] = h; OL[o] = l;
    }
}

__global__ void bias_cat_k(const float* __restrict__ a, const float* __restrict__ b,
                           float* __restrict__ o)
{
    int i = blockIdx.x * 256 + threadIdx.x;   // 1024
    o[i] = (i < D_) ? a[i] : b[i - D_];
}

// ---------------------------------------------------------------------------
__global__ void embed_gather_k(const int* __restrict__ src,
                               const float* __restrict__ table,
                               float* __restrict__ emb)
{
    int t = blockIdx.x;
    int v = src[t];
    for (int k = threadIdx.x; k < FEAT_; k += 256)
        emb[t * FEAT_ + k] = table[v * FEAT_ + k];
}

__global__ __launch_bounds__(256)
void pb_k(const float* __restrict__ frac, const float* __restrict__ pbW,
          const float* __restrict__ pbb, const float* __restrict__ pba,
          float* __restrict__ pb)
{
    int idx = blockIdx.x * 256 + threadIdx.x;
    int b = idx >> 14;
    int i = (idx >> 7) & 127;
    int j = idx & 127;
    float diff = (frac[b * T_ + j] - frac[b * T_ + i]) * 10.0f;
    float s = 0.f;
#pragma unroll
    for (int f = 0; f < NF_; ++f)
        s = fmaf(cosf(fmaf(diff, pbW[f], pbb[f])), pba[f], s);
    pb[idx] = s;
}

// kv[b,c] = sum_t K[b,t,c]*V[b,t,c]; K,V interleaved in KVb [BT][1024]
__global__ __launch_bounds__(256)
void kv_k(const float* __restrict__ KV, float* __restrict__ kv)
{
    int idx = blockIdx.x * 256 + threadIdx.x;
    int b = idx >> 9, c = idx & 511;
    const float* Kp = KV + (long)b * T_ * 1024 + c;
    float s = 0.f;
    for (int t = 0; t < T_; ++t) {
        const float* p = Kp + t * 1024;
        s = fmaf(p[0], p[D_], s);
    }
    kv[idx] = s;
}

// LayerNorm(x + add) -> out fp32 + split bf16
__global__ __launch_bounds__(256)
void ln_res_k(const float* __restrict__ x, const float* __restrict__ add,
              const float* __restrict__ g, const float* __restrict__ b,
              float* __restrict__ out, unsigned short* __restrict__ oh,
              unsigned short* __restrict__ ol)
{
    int wave = threadIdx.x >> 6, lane = threadIdx.x & 63;
    int row = blockIdx.x * 4 + wave;
    const float* xr = x   + (long)row * D_ + lane * 8;
    const float* ar = add + (long)row * D_ + lane * 8;
    float v[8]; float s = 0.f;
#pragma unroll
    for (int j = 0; j < 8; ++j) { v[j] = xr[j] + ar[j]; s += v[j]; }
#pragma unroll
    for (int off = 32; off > 0; off >>= 1) s += __shfl_xor(s, off, 64);
    float mean = s * (1.f / D_);
    float q = 0.f;
#pragma unroll
    for (int j = 0; j < 8; ++j) { float d = v[j] - mean; q += d * d; }
#pragma unroll
    for (int off = 32; off > 0; off >>= 1) q += __shfl_xor(q, off, 64);
    float inv = rsqrtf(q * (1.f / D_) + 1e-5f);
    float* orow = out + (long)row * D_ + lane * 8;
    unsigned short* hrow = oh + (long)row * D_ + lane * 8;
    unsigned short* lrow = ol + (long)row * D_ + lane * 8;
#pragma unroll
    for (int j = 0; j < 8; ++j) {
        int c = lane * 8 + j;
        float o = (v[j] - mean) * inv * g[c] + b[c];
        orow[j] = o;
        unsigned short hh, ll;
        split_bf(o, hh, ll);
        hrow[j] = hh; lrow[j] = ll;
    }
}

// LayerNorm(x + w0*eo0 + w1*eo1) -> out fp32 + split bf16
__global__ __launch_bounds__(256)
void ln_moe_k(const float* __restrict__ x, const float* __restrict__ eo,
              const int* __restrict__ tok_slot, const float* __restrict__ tok_w,
              const int* __restrict__ offsets,
              const float* __restrict__ g, const float* __restrict__ b,
              float* __restrict__ out, unsigned short* __restrict__ oh,
              unsigned short* __restrict__ ol)
{
    int wave = threadIdx.x >> 6, lane = threadIdx.x & 63;
    int row = blockIdx.x * 4 + wave;
    int  c0 = tok_slot[row * 2], c1 = tok_slot[row * 2 + 1];
    float w0 = tok_w[row * 2],  w1 = tok_w[row * 2 + 1];
    long r0 = offsets[c0 >> 12] + (c0 & 4095);
    long r1 = offsets[c1 >> 12] + (c1 & 4095);
    const float* xr = x  + (long)row * D_ + lane * 8;
    const float* e0 = eo + r0 * D_ + lane * 8;
    const float* e1 = eo + r1 * D_ + lane * 8;
    float v[8]; float s = 0.f;
#pragma unroll
    for (int j = 0; j < 8; ++j) {
        v[j] = xr[j] + w0 * e0[j] + w1 * e1[j];
        s += v[j];
    }
#pragma unroll
    for (int off = 32; off > 0; off >>= 1) s += __shfl_xor(s, off, 64);
    float mean = s * (1.f / D_);
    float q = 0.f;
#pragma unroll
    for (int j = 0; j < 8; ++j) { float d = v[j] - mean; q += d * d; }
#pragma unroll
    for (int off = 32; off > 0; off >>= 1) q += __shfl_xor(q, off, 64);
    float inv = rsqrtf(q * (1.f / D_) + 1e-5f);
    float* orow = out + (long)row * D_ + lane * 8;
    unsigned short* hrow = oh + (long)row * D_ + lane * 8;
    unsigned short* lrow = ol + (long)row * D_ + lane * 8;
#pragma unroll
    for (int j = 0; j < 8; ++j) {
        int c = lane * 8 + j;
        float o = (v[j] - mean) * inv * g[c] + b[c];
        orow[j] = o;
        unsigned short hh, ll;
        split_bf(o, hh, ll);
        hrow[j] = hh; lrow[j] = ll;
    }
}

// ---------------------------------------------------------------------------
// Gating + routing, block-aggregated.
// 64 blocks x 64 tokens. Per token: one wave computes the 8 logits
// (lane = expert(l&7) x d-chunk(l>>3), 3x shfl_xor chunk-reduce), gathers
// logits to all lanes, per-lane softmax + top2; lane 0 takes LDS-local slots.
// One global atomicAdd per (block, expert) -> 512 total.
// ---------------------------------------------------------------------------
__global__ __launch_bounds__(256)
void gate_k(const float* __restrict__ x, const float* __restrict__ gW,
            const float* __restrict__ gb, int* __restrict__ counts,
            int* __restrict__ tok_list, int* __restrict__ tok_slot,
            float* __restrict__ tok_w)
{
    __shared__ int scnt[E_];
    __shared__ int sbase[E_];
    __shared__ int sent[TPB_][2];      // (e<<12) | local_slot per token entry

    const int wave = threadIdx.x >> 6, lane = threadIdx.x & 63;
    const int e  = lane & 7;
    const int ch = lane >> 3;
    const int t0 = blockIdx.x * TPB_;

    if (threadIdx.x < E_) scnt[threadIdx.x] = 0;
    __syncthreads();

    for (int it = 0; it < TPB_ / 4; ++it) {
        const int tl = it * 4 + wave;
        const int t  = t0 + tl;

        // logit(e) partial over d-chunk ch (64 d's)
        const float4* x4 = (const float4*)(x + (long)t * D_ + ch * 64);
        const float*  wr = gW + (long)ch * 64 * E_ + e;
        float acc = 0.f;
#pragma unroll
        for (int d4 = 0; d4 < 16; ++d4) {
            float4 xv = x4[d4];
            acc = fmaf(xv.x, wr[(d4 * 4 + 0) * 8], acc);
            acc = fmaf(xv.y, wr[(d4 * 4 + 1) * 8], acc);
            acc = fmaf(xv.z, wr[(d4 * 4 + 2) * 8], acc);
            acc = fmaf(xv.w, wr[(d4 * 4 + 3) * 8], acc);
        }
        // reduce across the 8 chunk-groups (lanes differing in bits 3..5)
        acc += __shfl_xor(acc, 8, 64);
        acc += __shfl_xor(acc, 16, 64);
        acc += __shfl_xor(acc, 32, 64);
        acc += gb[e];                    // every lane now holds logit(lane&7)

        // gather all 8 logits into every lane (uniform, non-divergent)
        float lg[8];
#pragma unroll
        for (int ee = 0; ee < 8; ++ee)
            lg[ee] = __shfl(acc, (lane & 56) | ee, 64);

        // per-lane softmax + top2 (replicates old lane-0 serial code)
        float m = lg[0];
#pragma unroll
        for (int ee = 1; ee < 8; ++ee) m = fmaxf(m, lg[ee]);
        float p[8]; float s = 0.f;
#pragma unroll
        for (int ee = 0; ee < 8; ++ee) { p[ee] = expf(lg[ee] - m); s += p[ee]; }
        float inv = 1.f / s;
        int e1 = 0;
#pragma unroll
        for (int ee = 1; ee < 8; ++ee) if (p[ee] > p[e1]) e1 = ee;
        int e2 = (e1 == 0) ? 1 : 0;
#pragma unroll
        for (int ee = 0; ee < 8; ++ee) {
            if (ee == e1) continue;
            if (p[ee] > p[e2]) e2 = ee;
        }

        if (lane == 0) {
            int ls1 = atomicAdd(&scnt[e1], 1);
            int ls2 = atomicAdd(&scnt[e2], 1);
            sent[tl][0] = (e1 << 12) | ls1;
            sent[tl][1] = (e2 << 12) | ls2;
            tok_w[t * 2]     = p[e1] * inv;
            tok_w[t * 2 + 1] = p[e2] * inv;
        }
    }
    __syncthreads();

    if (threadIdx.x < E_)
        sbase[threadIdx.x] = atomicAdd(&counts[threadIdx.x], scnt[threadIdx.x]);
    __syncthreads();

    for (int tl = threadIdx.x; tl < TPB_; tl += 256) {
        const int t = t0 + tl;
#pragma unroll
        for (int kk = 0; kk < 2; ++kk) {
            int v    = sent[tl][kk];
            int ee   = v >> 12;
            int slot = sbase[ee] + (v & 4095);
            tok_list[ee * BT_ + slot] = t;
            tok_slot[t * 2 + kk] = (ee << 12) | slot;
        }
    }
}

__global__ void zero_counts_k(int* __restrict__ counts)
{
    if (threadIdx.x < E_) counts[threadIdx.x] = 0;
}

__global__ void scan_k(const int* __restrict__ counts, int* __restrict__ offsets)
{
    if (threadIdx.x == 0) {
        int s = 0;
        for (int e = 0; e < E_; ++e) { offsets[e] = s; s += counts[e]; }
    }
}

// ---------------------------------------------------------------------------
extern "C" void kernel_launch(void* const* d_in, const int* in_sizes, int n_in,
                              void* d_out, int out_size, void* d_ws, size_t ws_size,
                              hipStream_t stream)
{
    const int*   src   = (const int*)  d_in[0];
    const float* frac  = (const float*)d_in[1];
    const float* table = (const float*)d_in[2];
    const float* W_m2v = (const float*)d_in[3];
    const float* b_m2v = (const float*)d_in[4];
    const float* pbW   = (const float*)d_in[5];
    const float* pbb   = (const float*)d_in[6];
    const float* pba   = (const float*)d_in[7];
    const float* Wk    = (const float*)d_in[8];
    const float* bk    = (const float*)d_in[9];
    const float* Wv    = (const float*)d_in[10];
    const float* bv    = (const float*)d_in[11];
    const float* Wo    = (const float*)d_in[12];
    const float* bo    = (const float*)d_in[13];
    const float* ln1g  = (const float*)d_in[14];
    const float* ln1b  = (const float*)d_in[15];
    const float* ln2g  = (const float*)d_in[16];
    const float* ln2b  = (const float*)d_in[17];
    const float* gW    = (const float*)d_in[18];
    const float* gb    = (const float*)d_in[19];
    const float* eW1   = (const float*)d_in[20];
    const float* eb1   = (const float*)d_in[21];
    const float* eW2   = (const float*)d_in[22];
    const float* eb2   = (const float*)d_in[23];

    // ---- workspace layout (persistent) ----
    float* ws   = (float*)d_ws;
    float* x    = ws;  ws += (long)BT_ * D_;
    float* pb   = ws;  ws += (long)B_ * T_ * T_;
    float* eo   = ws;  ws += (long)2 * BT_ * D_;
    float* kv   = ws;  ws += B_ * D_;
    float* tokw = ws;  ws += 2 * BT_;
    float* kvbias = ws; ws += 2 * D_;
    unsigned short* us = (unsigned short*)ws;
    unsigned short* x_h   = us;  us += (long)BT_ * D_;
    unsigned short* x_l   = us;  us += (long)BT_ * D_;
    unsigned short* Wkv_h = us;  us += (long)2 * D_ * D_;   // [Wk^T ; Wv^T]
    unsigned short* Wkv_l = us;  us += (long)2 * D_ * D_;
    unsigned short* Wo_h  = us;  us += (long)D_ * D_;
    unsigned short* Wo_l  = us;  us += (long)D_ * D_;
    unsigned short* e1_h  = us;  us += (long)E_ * FF_ * D_;
    unsigned short* e1_l  = us;  us += (long)E_ * FF_ * D_;
    unsigned short* e2_h  = us;  us += (long)E_ * D_ * FF_;
    unsigned short* e2_l  = us;  us += (long)E_ * D_ * FF_;
    int* counts  = (int*)us;
    int* offsets = counts + 8;
    int* toklist = offsets + 8;
    int* tokslot = toklist + E_ * BT_;
    // ---- aliased region: {emb, KVb, tmp, wv pair} vs {h pair} ----
    char* ar = (char*)(tokslot + 2 * BT_);
    ar = (char*)(((size_t)ar + 255) & ~(size_t)255);
    unsigned short* h_h = (unsigned short*)ar;               // [2*BT][FF]
    unsigned short* h_l = h_h + (long)2 * BT_ * FF_;
    float* emb  = (float*)ar;
    float* KVb  = emb + (long)BT_ * FEAT_;                   // [BT][1024]
    float* tmp  = KVb + (long)BT_ * 2 * D_;
    unsigned short* wv_h = (unsigned short*)(tmp + (long)BT_ * D_);
    unsigned short* wv_l = wv_h + (long)BT_ * D_;

    // ---- embedder (fp32, fused split epilogue) ----
    embed_gather_k<<<BT_, 256, 0, stream>>>(src, table, emb);
    gemm_k<true, true><<<dim3(8, 64, 1), 256, 0, stream>>>(
        emb, W_m2v, b_m2v, x, x_h, x_l, FEAT_, FEAT_, D_, D_, 0, 0, 0, 0);

    // ---- fourier positional bias ----
    pb_k<<<(B_ * T_ * T_) / 256, 256, 0, stream>>>(frac, pbW, pbb, pba, pb);

    for (int i = 0; i < NL_; ++i) {
        // weight transposes: fp32 [K][N] -> split bf16 [N][K]
        transpose_split_k<<<dim3(16, 16, 1), 256, 0, stream>>>(
            Wk + (long)i * D_ * D_, Wkv_h, Wkv_l, D_, D_, 0, 0);
        transpose_split_k<<<dim3(16, 16, 1), 256, 0, stream>>>(
            Wv + (long)i * D_ * D_, Wkv_h + (long)D_ * D_, Wkv_l + (long)D_ * D_,
            D_, D_, 0, 0);
        transpose_split_k<<<dim3(16, 16, 1), 256, 0, stream>>>(
            Wo + (long)i * D_ * D_, Wo_h, Wo_l, D_, D_, 0, 0);
        transpose_split_k<<<dim3(64, 16, E_), 256, 0, stream>>>(
            eW1 + (long)i * E_ * D_ * FF_, e1_h, e1_l, D_, FF_,
            (long)D_ * FF_, (long)FF_ * D_);
        transpose_split_k<<<dim3(16, 64, E_), 256, 0, stream>>>(
            eW2 + (long)i * E_ * FF_ * D_, e2_h, e2_l, FF_, D_,
            (long)FF_ * D_, (long)D_ * FF_);
        bias_cat_k<<<4, 256, 0, stream>>>(bk + i * D_, bv + i * D_, kvbias);

        // merged K|V projection: [BT][1024] = x @ [Wk Wv]  (64-row m-tiles)
        mgemm_k<0, false, false><<<dim3(8, 64, 1), 256, 0, stream>>>(
            x_h, x_l, Wkv_h, Wkv_l, kvbias,
            KVb, nullptr, nullptr, BT_, D_, 2 * D_, 0, 0,
            nullptr, nullptr, nullptr);

        kv_k<<<(B_ * D_) / 256, 256, 0, stream>>>(KVb, kv);

        // wv[b] = pb[b] @ V[b] + kv[b]  (fp32, fused split epilogue -> wv pair)
        gemm_k<false, true><<<dim3(8, 2, B_), 256, 0, stream>>>(
            pb, KVb + D_, kv, nullptr, wv_h, wv_l, T_, T_, 2 * D_, D_,
            (long)T_ * T_, (long)T_ * 2 * D_, (long)T_ * D_, D_);

        // attention output projection
        mgemm_k<0, false, false><<<dim3(4, 64, 1), 256, 0, stream>>>(
            wv_h, wv_l, Wo_h, Wo_l, bo + i * D_,
            tmp, nullptr, nullptr, BT_, D_, D_, 0, 0, nullptr, nullptr, nullptr);

        // x = LN1(x + tmp)
        ln_res_k<<<BT_ / 4, 256, 0, stream>>>(x, tmp, ln1g + i * D_, ln1b + i * D_,
                                              x, x_h, x_l);

        // gating + routing (block-aggregated atomics)
        zero_counts_k<<<1, 64, 0, stream>>>(counts);
        gate_k<<<GB_, 256, 0, stream>>>(x, gW + (long)i * D_ * E_, gb + i * E_,
                                        counts, toklist, tokslot, tokw);
        scan_k<<<1, 1, 0, stream>>>(counts, offsets);

        // MoE expert GEMMs (split MFMA, 64-row m-tiles)
        mgemm_k<1, true, true><<<dim3(16, 64, E_), 256, 0, stream>>>(
            x_h, x_l, e1_h, e1_l, eb1 + (long)i * E_ * FF_,
            nullptr, h_h, h_l, 0, D_, FF_,
            (long)FF_ * D_, FF_, counts, offsets, toklist);
        mgemm_k<2, false, false><<<dim3(4, 64, E_), 256, 0, stream>>>(
            h_h, h_l, e2_h, e2_l, eb2 + (long)i * E_ * D_,
            eo, nullptr, nullptr, 0, FF_, D_,
            (long)D_ * FF_, D_, counts, offsets, toklist);

        // x = LN2(x + w0*eo0 + w1*eo1)
        float* dst = (i == NL_ - 1) ? (float*)d_out : x;
        ln_moe_k<<<BT_ / 4, 256, 0, stream>>>(x, eo, tokslot, tokw, offsets,
                                              ln2g + i * D_, ln2b + i * D_,
                                              dst, x_h, x_l);
    }
}

// Round 4
// 1182.718 us; speedup vs baseline: 1.0911x; 1.0363x over previous
//
#include <hip/hip_runtime.h>
#include <math.h>

#define B_    32
#define T_    128
#define D_    512
#define FF_   2048
#define E_    8
#define NL_   3
#define NF_   16
#define FEAT_ 200
#define BT_   4096   // B*T

// gate routing: 64 blocks x 64 tokens each -> 512 global atomics (vs 8192)
#define GB_   64
#define TPB_  (BT_ / GB_)   // 64 tokens per block

typedef short bf16x8 __attribute__((ext_vector_type(8)));
typedef float f32x4  __attribute__((ext_vector_type(4)));

__device__ inline unsigned short f2bf(float f) {
    unsigned u = __float_as_uint(f);
    unsigned r = (u + 0x7fffu + ((u >> 16) & 1u)) >> 16;   // RNE
    return (unsigned short)r;
}
// f = hi + lo + eps, |eps| <= 2^-18 |f|
__device__ inline void split_bf(float f, unsigned short& h, unsigned short& l) {
    h = f2bf(f);
    float fh = __uint_as_float(((unsigned)h) << 16);
    l = f2bf(f - fh);
}

// async HBM->LDS DMA, 16B/lane, no VGPR round-trip. LDS dest is
// wave-uniform base + lane*16 (HW rule).
__device__ __forceinline__ void ld_g2l(const unsigned short* g, unsigned short* l)
{
    __builtin_amdgcn_global_load_lds(
        (const __attribute__((address_space(1))) unsigned int*)(uintptr_t)g,
        (__attribute__((address_space(3))) unsigned int*)(uintptr_t)l,
        16, 0, 0);
}

// ---------------------------------------------------------------------------
// Split-bf16 MFMA GEMM, DMA-staged + ping-pong LDS double buffer.
// C = A @ Bt^T + bias, fp32-equivalent precision (3-term MFMA).
// A as (Ah, Al) bf16 [M][K]; Bt as (Bh, Bl) [N][K] (K-contig).
// Tile 128x128, BK=32, **8 waves (512 thr)** as 4m x 2n, each wave 32x64 via
// 2x4 of 16x16x32 MFMA. LDS 64 KB -> 2 blocks/CU -> 16 waves/CU (2x the
// 4-wave version) at the SAME bytes/FLOP: TLP hides the per-iter DMA drain.
// LDS per buffer: 4 arrays (Ah,Al,Bh,Bl) of [128 rows][32 shorts]; within a
// row, global 16B-seg s lands at pos p = s ^ ((r>>1)&3) -> frag ds_read_b128
// is 2-way bank aliased (free). Staging: 1 ld_g2l per thread per array
// (512 thr x 16 B = 8 KB array), row = tid>>2, pos = tid&3.
// MODE 0: direct rows. MODE 1: A rows via tok_list[z], C rows offsets[z]+m.
// MODE 2: A and C rows at offsets[z]+m.
// ---------------------------------------------------------------------------
template <int MODE, bool SPLITOUT, bool RELU>
__global__ __launch_bounds__(512)
void mgemm_k(const unsigned short* __restrict__ Ah, const unsigned short* __restrict__ Al,
             const unsigned short* __restrict__ Bh, const unsigned short* __restrict__ Bl,
             const float* __restrict__ bias,
             float* __restrict__ Cf, unsigned short* __restrict__ Ch,
             unsigned short* __restrict__ Cl,
             int M, int K, int N, long strB, int strBias,
             const int* __restrict__ counts, const int* __restrict__ offsets,
             const int* __restrict__ tok_list)
{
    const int z  = blockIdx.z;
    const int m0 = blockIdx.y * 128, n0 = blockIdx.x * 128;
    int rows, rowoff = 0;
    if constexpr (MODE != 0) {
        rows = counts[z];
        if (m0 >= rows) return;
        rowoff = offsets[z];
    } else {
        rows = M;
    }
    const unsigned short* Bhb = Bh + (long)z * strB;
    const unsigned short* Blb = Bl + (long)z * strB;
    const float* biasb = bias + (long)z * strBias;

    // 2 buffers x 4 arrays x 4096 shorts (8 KB) = 64 KB
    __shared__ unsigned short S[2][4 * 4096];

    const int tid  = threadIdx.x;
    const int w    = tid >> 6, lane = tid & 63;
    const int wm = w & 3, wn = w >> 2;           // 4m x 2n wave grid
    const int l15 = lane & 15, quad = lane >> 4;

    // staging map: thread covers tile row r = tid>>2, LDS pos p = tid&3,
    // global seg s = p ^ ((r>>1)&3) = p ^ ((tid>>3)&3).
    // LDS dest (wave-uniform base, HW adds lane*16B): array + w*512 shorts.
    const int srow = tid >> 2;
    const int sseg = (tid & 3) ^ ((tid >> 3) & 3);
    const int lbW  = w * 512;                    // uniform short-offset in array

    long gaA;
    if constexpr (MODE == 1) {
        int m_a = m0 + srow; if (m_a >= rows) m_a = rows - 1;
        gaA = tok_list[z * BT_ + m_a];
    } else if constexpr (MODE == 2) {
        int m_a = m0 + srow; if (m_a >= rows) m_a = rows - 1;
        gaA = (long)rowoff + m_a;
    } else {
        gaA = m0 + srow;
    }
    const long aoff = gaA * (long)K + sseg * 8;
    const long boff = (long)(n0 + srow) * K + sseg * 8;

    f32x4 acc[2][4];
#pragma unroll
    for (int i = 0; i < 2; ++i)
#pragma unroll
        for (int j = 0; j < 4; ++j) acc[i][j] = (f32x4)0.f;

    const int xq = quad ^ ((l15 >> 1) & 3);          // swizzled read pos

    // ---- prologue: DMA tile 0 into buffer 0 ----
    {
        unsigned short* Sb = S[0];
        ld_g2l(Ah  + aoff, Sb + 0 * 4096 + lbW);
        ld_g2l(Al  + aoff, Sb + 1 * 4096 + lbW);
        ld_g2l(Bhb + boff, Sb + 2 * 4096 + lbW);
        ld_g2l(Blb + boff, Sb + 3 * 4096 + lbW);
    }

    unsigned short* Scur = S[0];
    unsigned short* Snxt = S[1];

    for (int k0 = 0; k0 < K; k0 += 32) {
        __syncthreads();        // drains DMA for tile k0 (in flight one full iter)

        if (k0 + 32 < K) {      // prefetch tile k0+32 into the other buffer
            int kn = k0 + 32;
            ld_g2l(Ah  + aoff + kn, Snxt + 0 * 4096 + lbW);
            ld_g2l(Al  + aoff + kn, Snxt + 1 * 4096 + lbW);
            ld_g2l(Bhb + boff + kn, Snxt + 2 * 4096 + lbW);
            ld_g2l(Blb + boff + kn, Snxt + 3 * 4096 + lbW);
        }

        bf16x8 ah2[2], al2[2], bh4[4], bl4[4];
#pragma unroll
        for (int i = 0; i < 2; ++i) {
            int ro = (wm * 32 + i * 16 + l15) * 32 + xq * 8;
            ah2[i] = *(const bf16x8*)&Scur[0 * 4096 + ro];
            al2[i] = *(const bf16x8*)&Scur[1 * 4096 + ro];
        }
#pragma unroll
        for (int j = 0; j < 4; ++j) {
            int ro = (wn * 64 + j * 16 + l15) * 32 + xq * 8;
            bh4[j] = *(const bf16x8*)&Scur[2 * 4096 + ro];
            bl4[j] = *(const bf16x8*)&Scur[3 * 4096 + ro];
        }
#pragma unroll
        for (int i = 0; i < 2; ++i)
#pragma unroll
            for (int j = 0; j < 4; ++j) {
                acc[i][j] = __builtin_amdgcn_mfma_f32_16x16x32_bf16(al2[i], bh4[j], acc[i][j], 0, 0, 0);
                acc[i][j] = __builtin_amdgcn_mfma_f32_16x16x32_bf16(ah2[i], bl4[j], acc[i][j], 0, 0, 0);
                acc[i][j] = __builtin_amdgcn_mfma_f32_16x16x32_bf16(ah2[i], bh4[j], acc[i][j], 0, 0, 0);
            }

        unsigned short* t = Scur; Scur = Snxt; Snxt = t;
    }

    // C/D layout: col = lane&15, row = quad*4 + reg
#pragma unroll
    for (int i = 0; i < 2; ++i) {
#pragma unroll
        for (int r = 0; r < 4; ++r) {
            int gm = m0 + wm * 32 + i * 16 + quad * 4 + r;
            if (MODE != 0 && gm >= rows) continue;
            long crow = (MODE != 0) ? ((long)rowoff + gm) : (long)gm;
#pragma unroll
            for (int j = 0; j < 4; ++j) {
                int col = n0 + wn * 64 + j * 16 + l15;
                float v = acc[i][j][r] + biasb[col];
                if constexpr (RELU) v = fmaxf(v, 0.f);
                if constexpr (SPLITOUT) {
                    unsigned short h, l;
                    split_bf(v, h, l);
                    Ch[crow * (long)N + col] = h;
                    Cl[crow * (long)N + col] = l;
                } else {
                    Cf[crow * (long)N + col] = v;
                }
            }
        }
    }
}

// ---------------------------------------------------------------------------
// fp32 SGEMM (embed GEMM K=200, batched pb@V). Optional fused split-bf16 out.
// ---------------------------------------------------------------------------
template <bool WF32, bool SPLIT>
__global__ __launch_bounds__(256)
void gemm_k(const float* __restrict__ A, const float* __restrict__ Bm,
            const float* __restrict__ bias, float* __restrict__ C,
            unsigned short* __restrict__ Oh, unsigned short* __restrict__ Ol,
            int K, int lda, int ldb, int ldc,
            long strA, long strB, long strC, int strBias)
{
    const int z  = blockIdx.z;
    const int m0 = blockIdx.y * 64, n0 = blockIdx.x * 64;
    const float* Ab    = A    + (long)z * strA;
    const float* Bb    = Bm   + (long)z * strB;
    const float* biasb = bias + (long)z * strBias;

    __shared__ float As[16][68];
    __shared__ float Bs[16][64];

    const int tid = threadIdx.x;
    const int tx  = tid & 15, ty = tid >> 4;
    const int ar  = tid >> 2;
    const int akc = (tid & 3) * 4;
    const float* Arow = Ab + (long)(m0 + ar) * lda;
    const int bkr = tid >> 4;
    const int bnc = (tid & 15) * 4;

    float acc[4][4];
#pragma unroll
    for (int i = 0; i < 4; ++i)
#pragma unroll
        for (int j = 0; j < 4; ++j) acc[i][j] = 0.f;

    for (int k0 = 0; k0 < K; k0 += 16) {
        if (k0 + 16 <= K) {
            float4 a = *(const float4*)(Arow + k0 + akc);
            As[akc + 0][ar] = a.x; As[akc + 1][ar] = a.y;
            As[akc + 2][ar] = a.z; As[akc + 3][ar] = a.w;
        } else {
#pragma unroll
            for (int j = 0; j < 4; ++j) {
                int kk = k0 + akc + j;
                As[akc + j][ar] = (kk < K) ? Arow[kk] : 0.f;
            }
        }
        {
            int kk = k0 + bkr;
            float4 b;
            if (kk < K) b = *(const float4*)(Bb + (long)kk * ldb + n0 + bnc);
            else        b = make_float4(0.f, 0.f, 0.f, 0.f);
            *(float4*)&Bs[bkr][bnc] = b;
        }
        __syncthreads();
#pragma unroll
        for (int k = 0; k < 16; ++k) {
            float4 av = *(const float4*)&As[k][ty * 4];
            float4 bv = *(const float4*)&Bs[k][tx * 4];
            float am[4] = {av.x, av.y, av.z, av.w};
            float bn[4] = {bv.x, bv.y, bv.z, bv.w};
#pragma unroll
            for (int i = 0; i < 4; ++i)
#pragma unroll
                for (int j = 0; j < 4; ++j)
                    acc[i][j] = fmaf(am[i], bn[j], acc[i][j]);
        }
        __syncthreads();
    }
#pragma unroll
    for (int i = 0; i < 4; ++i) {
        long base = ((long)z * strC) + (long)(m0 + ty * 4 + i) * ldc + n0 + tx * 4;
        const float* bp = biasb + n0 + tx * 4;
#pragma unroll
        for (int j = 0; j < 4; ++j) {
            float v = acc[i][j] + bp[j];
            if constexpr (WF32) C[base + j] = v;
            if constexpr (SPLIT) {
                unsigned short h, l;
                split_bf(v, h, l);
                Oh[base + j] = h;
                Ol[base + j] = l;
            }
        }
    }
}

// ---------------------------------------------------------------------------
// fp32 [R][C] -> split-bf16 [C][R] (hi, lo), batched over z
// ---------------------------------------------------------------------------
__global__ __launch_bounds__(256)
void transpose_split_k(const float* __restrict__ in,
                       unsigned short* __restrict__ oh, unsigned short* __restrict__ ol,
                       int R, int C, long strIn, long strOut)
{
    __shared__ float tile[32][33];
    const float* I = in + (long)blockIdx.z * strIn;
    unsigned short* OH = oh + (long)blockIdx.z * strOut;
    unsigned short* OL = ol + (long)blockIdx.z * strOut;
    int c0 = blockIdx.x * 32, r0 = blockIdx.y * 32;
    int tx = threadIdx.x & 31, ty = threadIdx.x >> 5;
#pragma unroll
    for (int i = 0; i < 4; ++i)
        tile[ty + i * 8][tx] = I[(long)(r0 + ty + i * 8) * C + c0 + tx];
    __syncthreads();
#pragma unroll
    for (int i = 0; i < 4; ++i) {
        unsigned short h, l;
        split_bf(tile[tx][ty + i * 8], h, l);
        long o = (long)(c0 + ty + i * 8) * R + r0 + tx;
        OH[o] = h; OL[o] = l;
    }
}

__global__ void bias_cat_k(const float* __restrict__ a, const float* __restrict__ b,
                           float* __restrict__ o)
{
    int i = blockIdx.x * 256 + threadIdx.x;   // 1024
    o[i] = (i < D_) ? a[i] : b[i - D_];
}

// ---------------------------------------------------------------------------
__global__ void embed_gather_k(const int* __restrict__ src,
                               const float* __restrict__ table,
                               float* __restrict__ emb)
{
    int t = blockIdx.x;
    int v = src[t];
    for (int k = threadIdx.x; k < FEAT_; k += 256)
        emb[t * FEAT_ + k] = table[v * FEAT_ + k];
}

__global__ __launch_bounds__(256)
void pb_k(const float* __restrict__ frac, const float* __restrict__ pbW,
          const float* __restrict__ pbb, const float* __restrict__ pba,
          float* __restrict__ pb)
{
    int idx = blockIdx.x * 256 + threadIdx.x;
    int b = idx >> 14;
    int i = (idx >> 7) & 127;
    int j = idx & 127;
    float diff = (frac[b * T_ + j] - frac[b * T_ + i]) * 10.0f;
    float s = 0.f;
#pragma unroll
    for (int f = 0; f < NF_; ++f)
        s = fmaf(cosf(fmaf(diff, pbW[f], pbb[f])), pba[f], s);
    pb[idx] = s;
}

// kv[b,c] = sum_t K[b,t,c]*V[b,t,c]; K,V interleaved in KVb [BT][1024]
__global__ __launch_bounds__(256)
void kv_k(const float* __restrict__ KV, float* __restrict__ kv)
{
    int idx = blockIdx.x * 256 + threadIdx.x;
    int b = idx >> 9, c = idx & 511;
    const float* Kp = KV + (long)b * T_ * 1024 + c;
    float s = 0.f;
    for (int t = 0; t < T_; ++t) {
        const float* p = Kp + t * 1024;
        s = fmaf(p[0], p[D_], s);
    }
    kv[idx] = s;
}

// LayerNorm(x + add) -> out fp32 + split bf16
__global__ __launch_bounds__(256)
void ln_res_k(const float* __restrict__ x, const float* __restrict__ add,
              const float* __restrict__ g, const float* __restrict__ b,
              float* __restrict__ out, unsigned short* __restrict__ oh,
              unsigned short* __restrict__ ol)
{
    int wave = threadIdx.x >> 6, lane = threadIdx.x & 63;
    int row = blockIdx.x * 4 + wave;
    const float* xr = x   + (long)row * D_ + lane * 8;
    const float* ar = add + (long)row * D_ + lane * 8;
    float v[8]; float s = 0.f;
#pragma unroll
    for (int j = 0; j < 8; ++j) { v[j] = xr[j] + ar[j]; s += v[j]; }
#pragma unroll
    for (int off = 32; off > 0; off >>= 1) s += __shfl_xor(s, off, 64);
    float mean = s * (1.f / D_);
    float q = 0.f;
#pragma unroll
    for (int j = 0; j < 8; ++j) { float d = v[j] - mean; q += d * d; }
#pragma unroll
    for (int off = 32; off > 0; off >>= 1) q += __shfl_xor(q, off, 64);
    float inv = rsqrtf(q * (1.f / D_) + 1e-5f);
    float* orow = out + (long)row * D_ + lane * 8;
    unsigned short* hrow = oh + (long)row * D_ + lane * 8;
    unsigned short* lrow = ol + (long)row * D_ + lane * 8;
#pragma unroll
    for (int j = 0; j < 8; ++j) {
        int c = lane * 8 + j;
        float o = (v[j] - mean) * inv * g[c] + b[c];
        orow[j] = o;
        unsigned short hh, ll;
        split_bf(o, hh, ll);
        hrow[j] = hh; lrow[j] = ll;
    }
}

// LayerNorm(x + w0*eo0 + w1*eo1) -> out fp32 + split bf16
__global__ __launch_bounds__(256)
void ln_moe_k(const float* __restrict__ x, const float* __restrict__ eo,
              const int* __restrict__ tok_slot, const float* __restrict__ tok_w,
              const int* __restrict__ offsets,
              const float* __restrict__ g, const float* __restrict__ b,
              float* __restrict__ out, unsigned short* __restrict__ oh,
              unsigned short* __restrict__ ol)
{
    int wave = threadIdx.x >> 6, lane = threadIdx.x & 63;
    int row = blockIdx.x * 4 + wave;
    int  c0 = tok_slot[row * 2], c1 = tok_slot[row * 2 + 1];
    float w0 = tok_w[row * 2],  w1 = tok_w[row * 2 + 1];
    long r0 = offsets[c0 >> 12] + (c0 & 4095);
    long r1 = offsets[c1 >> 12] + (c1 & 4095);
    const float* xr = x  + (long)row * D_ + lane * 8;
    const float* e0 = eo + r0 * D_ + lane * 8;
    const float* e1 = eo + r1 * D_ + lane * 8;
    float v[8]; float s = 0.f;
#pragma unroll
    for (int j = 0; j < 8; ++j) {
        v[j] = xr[j] + w0 * e0[j] + w1 * e1[j];
        s += v[j];
    }
#pragma unroll
    for (int off = 32; off > 0; off >>= 1) s += __shfl_xor(s, off, 64);
    float mean = s * (1.f / D_);
    float q = 0.f;
#pragma unroll
    for (int j = 0; j < 8; ++j) { float d = v[j] - mean; q += d * d; }
#pragma unroll
    for (int off = 32; off > 0; off >>= 1) q += __shfl_xor(q, off, 64);
    float inv = rsqrtf(q * (1.f / D_) + 1e-5f);
    float* orow = out + (long)row * D_ + lane * 8;
    unsigned short* hrow = oh + (long)row * D_ + lane * 8;
    unsigned short* lrow = ol + (long)row * D_ + lane * 8;
#pragma unroll
    for (int j = 0; j < 8; ++j) {
        int c = lane * 8 + j;
        float o = (v[j] - mean) * inv * g[c] + b[c];
        orow[j] = o;
        unsigned short hh, ll;
        split_bf(o, hh, ll);
        hrow[j] = hh; lrow[j] = ll;
    }
}

// ---------------------------------------------------------------------------
// Gating + routing, block-aggregated.
// 64 blocks x 64 tokens. Per token: one wave computes the 8 logits
// (lane = expert(l&7) x d-chunk(l>>3), 3x shfl_xor chunk-reduce), gathers
// logits to all lanes, per-lane softmax + top2; lane 0 takes LDS-local slots.
// One global atomicAdd per (block, expert) -> 512 total.
// ---------------------------------------------------------------------------
__global__ __launch_bounds__(256)
void gate_k(const float* __restrict__ x, const float* __restrict__ gW,
            const float* __restrict__ gb, int* __restrict__ counts,
            int* __restrict__ tok_list, int* __restrict__ tok_slot,
            float* __restrict__ tok_w)
{
    __shared__ int scnt[E_];
    __shared__ int sbase[E_];
    __shared__ int sent[TPB_][2];      // (e<<12) | local_slot per token entry

    const int wave = threadIdx.x >> 6, lane = threadIdx.x & 63;
    const int e  = lane & 7;
    const int ch = lane >> 3;
    const int t0 = blockIdx.x * TPB_;

    if (threadIdx.x < E_) scnt[threadIdx.x] = 0;
    __syncthreads();

    for (int it = 0; it < TPB_ / 4; ++it) {
        const int tl = it * 4 + wave;
        const int t  = t0 + tl;

        // logit(e) partial over d-chunk ch (64 d's)
        const float4* x4 = (const float4*)(x + (long)t * D_ + ch * 64);
        const float*  wr = gW + (long)ch * 64 * E_ + e;
        float acc = 0.f;
#pragma unroll
        for (int d4 = 0; d4 < 16; ++d4) {
            float4 xv = x4[d4];
            acc = fmaf(xv.x, wr[(d4 * 4 + 0) * 8], acc);
            acc = fmaf(xv.y, wr[(d4 * 4 + 1) * 8], acc);
            acc = fmaf(xv.z, wr[(d4 * 4 + 2) * 8], acc);
            acc = fmaf(xv.w, wr[(d4 * 4 + 3) * 8], acc);
        }
        // reduce across the 8 chunk-groups (lanes differing in bits 3..5)
        acc += __shfl_xor(acc, 8, 64);
        acc += __shfl_xor(acc, 16, 64);
        acc += __shfl_xor(acc, 32, 64);
        acc += gb[e];                    // every lane now holds logit(lane&7)

        // gather all 8 logits into every lane (uniform, non-divergent)
        float lg[8];
#pragma unroll
        for (int ee = 0; ee < 8; ++ee)
            lg[ee] = __shfl(acc, (lane & 56) | ee, 64);

        // per-lane softmax + top2 (replicates old lane-0 serial code)
        float m = lg[0];
#pragma unroll
        for (int ee = 1; ee < 8; ++ee) m = fmaxf(m, lg[ee]);
        float p[8]; float s = 0.f;
#pragma unroll
        for (int ee = 0; ee < 8; ++ee) { p[ee] = expf(lg[ee] - m); s += p[ee]; }
        float inv = 1.f / s;
        int e1 = 0;
#pragma unroll
        for (int ee = 1; ee < 8; ++ee) if (p[ee] > p[e1]) e1 = ee;
        int e2 = (e1 == 0) ? 1 : 0;
#pragma unroll
        for (int ee = 0; ee < 8; ++ee) {
            if (ee == e1) continue;
            if (p[ee] > p[e2]) e2 = ee;
        }

        if (lane == 0) {
            int ls1 = atomicAdd(&scnt[e1], 1);
            int ls2 = atomicAdd(&scnt[e2], 1);
            sent[tl][0] = (e1 << 12) | ls1;
            sent[tl][1] = (e2 << 12) | ls2;
            tok_w[t * 2]     = p[e1] * inv;
            tok_w[t * 2 + 1] = p[e2] * inv;
        }
    }
    __syncthreads();

    if (threadIdx.x < E_)
        sbase[threadIdx.x] = atomicAdd(&counts[threadIdx.x], scnt[threadIdx.x]);
    __syncthreads();

    for (int tl = threadIdx.x; tl < TPB_; tl += 256) {
        const int t = t0 + tl;
#pragma unroll
        for (int kk = 0; kk < 2; ++kk) {
            int v    = sent[tl][kk];
            int ee   = v >> 12;
            int slot = sbase[ee] + (v & 4095);
            tok_list[ee * BT_ + slot] = t;
            tok_slot[t * 2 + kk] = (ee << 12) | slot;
        }
    }
}

__global__ void zero_counts_k(int* __restrict__ counts)
{
    if (threadIdx.x < E_) counts[threadIdx.x] = 0;
}

__global__ void scan_k(const int* __restrict__ counts, int* __restrict__ offsets)
{
    if (threadIdx.x == 0) {
        int s = 0;
        for (int e = 0; e < E_; ++e) { offsets[e] = s; s += counts[e]; }
    }
}

// ---------------------------------------------------------------------------
extern "C" void kernel_launch(void* const* d_in, const int* in_sizes, int n_in,
                              void* d_out, int out_size, void* d_ws, size_t ws_size,
                              hipStream_t stream)
{
    const int*   src   = (const int*)  d_in[0];
    const float* frac  = (const float*)d_in[1];
    const float* table = (const float*)d_in[2];
    const float* W_m2v = (const float*)d_in[3];
    const float* b_m2v = (const float*)d_in[4];
    const float* pbW   = (const float*)d_in[5];
    const float* pbb   = (const float*)d_in[6];
    const float* pba   = (const float*)d_in[7];
    const float* Wk    = (const float*)d_in[8];
    const float* bk    = (const float*)d_in[9];
    const float* Wv    = (const float*)d_in[10];
    const float* bv    = (const float*)d_in[11];
    const float* Wo    = (const float*)d_in[12];
    const float* bo    = (const float*)d_in[13];
    const float* ln1g  = (const float*)d_in[14];
    const float* ln1b  = (const float*)d_in[15];
    const float* ln2g  = (const float*)d_in[16];
    const float* ln2b  = (const float*)d_in[17];
    const float* gW    = (const float*)d_in[18];
    const float* gb    = (const float*)d_in[19];
    const float* eW1   = (const float*)d_in[20];
    const float* eb1   = (const float*)d_in[21];
    const float* eW2   = (const float*)d_in[22];
    const float* eb2   = (const float*)d_in[23];

    // ---- workspace layout (persistent) ----
    float* ws   = (float*)d_ws;
    float* x    = ws;  ws += (long)BT_ * D_;
    float* pb   = ws;  ws += (long)B_ * T_ * T_;
    float* eo   = ws;  ws += (long)2 * BT_ * D_;
    float* kv   = ws;  ws += B_ * D_;
    float* tokw = ws;  ws += 2 * BT_;
    float* kvbias = ws; ws += 2 * D_;
    unsigned short* us = (unsigned short*)ws;
    unsigned short* x_h   = us;  us += (long)BT_ * D_;
    unsigned short* x_l   = us;  us += (long)BT_ * D_;
    unsigned short* Wkv_h = us;  us += (long)2 * D_ * D_;   // [Wk^T ; Wv^T]
    unsigned short* Wkv_l = us;  us += (long)2 * D_ * D_;
    unsigned short* Wo_h  = us;  us += (long)D_ * D_;
    unsigned short* Wo_l  = us;  us += (long)D_ * D_;
    unsigned short* e1_h  = us;  us += (long)E_ * FF_ * D_;
    unsigned short* e1_l  = us;  us += (long)E_ * FF_ * D_;
    unsigned short* e2_h  = us;  us += (long)E_ * D_ * FF_;
    unsigned short* e2_l  = us;  us += (long)E_ * D_ * FF_;
    int* counts  = (int*)us;
    int* offsets = counts + 8;
    int* toklist = offsets + 8;
    int* tokslot = toklist + E_ * BT_;
    // ---- aliased region: {emb, KVb, tmp, wv pair} vs {h pair} ----
    char* ar = (char*)(tokslot + 2 * BT_);
    ar = (char*)(((size_t)ar + 255) & ~(size_t)255);
    unsigned short* h_h = (unsigned short*)ar;               // [2*BT][FF]
    unsigned short* h_l = h_h + (long)2 * BT_ * FF_;
    float* emb  = (float*)ar;
    float* KVb  = emb + (long)BT_ * FEAT_;                   // [BT][1024]
    float* tmp  = KVb + (long)BT_ * 2 * D_;
    unsigned short* wv_h = (unsigned short*)(tmp + (long)BT_ * D_);
    unsigned short* wv_l = wv_h + (long)BT_ * D_;

    // ---- embedder (fp32, fused split epilogue) ----
    embed_gather_k<<<BT_, 256, 0, stream>>>(src, table, emb);
    gemm_k<true, true><<<dim3(8, 64, 1), 256, 0, stream>>>(
        emb, W_m2v, b_m2v, x, x_h, x_l, FEAT_, FEAT_, D_, D_, 0, 0, 0, 0);

    // ---- fourier positional bias ----
    pb_k<<<(B_ * T_ * T_) / 256, 256, 0, stream>>>(frac, pbW, pbb, pba, pb);

    for (int i = 0; i < NL_; ++i) {
        // weight transposes: fp32 [K][N] -> split bf16 [N][K]
        transpose_split_k<<<dim3(16, 16, 1), 256, 0, stream>>>(
            Wk + (long)i * D_ * D_, Wkv_h, Wkv_l, D_, D_, 0, 0);
        transpose_split_k<<<dim3(16, 16, 1), 256, 0, stream>>>(
            Wv + (long)i * D_ * D_, Wkv_h + (long)D_ * D_, Wkv_l + (long)D_ * D_,
            D_, D_, 0, 0);
        transpose_split_k<<<dim3(16, 16, 1), 256, 0, stream>>>(
            Wo + (long)i * D_ * D_, Wo_h, Wo_l, D_, D_, 0, 0);
        transpose_split_k<<<dim3(64, 16, E_), 256, 0, stream>>>(
            eW1 + (long)i * E_ * D_ * FF_, e1_h, e1_l, D_, FF_,
            (long)D_ * FF_, (long)FF_ * D_);
        transpose_split_k<<<dim3(16, 64, E_), 256, 0, stream>>>(
            eW2 + (long)i * E_ * FF_ * D_, e2_h, e2_l, FF_, D_,
            (long)FF_ * D_, (long)D_ * FF_);
        bias_cat_k<<<4, 256, 0, stream>>>(bk + i * D_, bv + i * D_, kvbias);

        // merged K|V projection: [BT][1024] = x @ [Wk Wv]
        mgemm_k<0, false, false><<<dim3(8, 32, 1), 512, 0, stream>>>(
            x_h, x_l, Wkv_h, Wkv_l, kvbias,
            KVb, nullptr, nullptr, BT_, D_, 2 * D_, 0, 0,
            nullptr, nullptr, nullptr);

        kv_k<<<(B_ * D_) / 256, 256, 0, stream>>>(KVb, kv);

        // wv[b] = pb[b] @ V[b] + kv[b]  (fp32, fused split epilogue -> wv pair)
        gemm_k<false, true><<<dim3(8, 2, B_), 256, 0, stream>>>(
            pb, KVb + D_, kv, nullptr, wv_h, wv_l, T_, T_, 2 * D_, D_,
            (long)T_ * T_, (long)T_ * 2 * D_, (long)T_ * D_, D_);

        // attention output projection
        mgemm_k<0, false, false><<<dim3(4, 32, 1), 512, 0, stream>>>(
            wv_h, wv_l, Wo_h, Wo_l, bo + i * D_,
            tmp, nullptr, nullptr, BT_, D_, D_, 0, 0, nullptr, nullptr, nullptr);

        // x = LN1(x + tmp)
        ln_res_k<<<BT_ / 4, 256, 0, stream>>>(x, tmp, ln1g + i * D_, ln1b + i * D_,
                                              x, x_h, x_l);

        // gating + routing (block-aggregated atomics)
        zero_counts_k<<<1, 64, 0, stream>>>(counts);
        gate_k<<<GB_, 256, 0, stream>>>(x, gW + (long)i * D_ * E_, gb + i * E_,
                                        counts, toklist, tokslot, tokw);
        scan_k<<<1, 1, 0, stream>>>(counts, offsets);

        // MoE expert GEMMs (split MFMA)
        mgemm_k<1, true, true><<<dim3(16, 32, E_), 512, 0, stream>>>(
            x_h, x_l, e1_h, e1_l, eb1 + (long)i * E_ * FF_,
            nullptr, h_h, h_l, 0, D_, FF_,
            (long)FF_ * D_, FF_, counts, offsets, toklist);
        mgemm_k<2, false, false><<<dim3(4, 32, E_), 512, 0, stream>>>(
            h_h, h_l, e2_h, e2_l, eb2 + (long)i * E_ * D_,
            eo, nullptr, nullptr, 0, FF_, D_,
            (long)D_ * FF_, D_, counts, offsets, toklist);

        // x = LN2(x + w0*eo0 + w1*eo1)
        float* dst = (i == NL_ - 1) ? (float*)d_out : x;
        ln_moe_k<<<BT_ / 4, 256, 0, stream>>>(x, eo, tokslot, tokw, offsets,
                                              ln2g + i * D_, ln2b + i * D_,
                                              dst, x_h, x_l);
    }
}